// Round 9
// baseline (383.880 us; speedup 1.0000x reference)
//
#include <hip/hip_runtime.h>
#include <hip/hip_bf16.h>
#include <hip/hip_fp16.h>

#define N_NODES 50000
#define N_EDGES 1600000
#define N_GRAPHS 64
#define G1BLKS 1563            // ceil(N_NODES/32) gemm1 blocks in mega kernel

// ---------- helpers ----------
__device__ __forceinline__ unsigned fenc(float x) {
    unsigned u = __float_as_uint(x);
    return (u & 0x80000000u) ? ~u : (u | 0x80000000u);
}
__device__ __forceinline__ float fdec(unsigned e) {
    return (e & 0x80000000u) ? __uint_as_float(e & 0x7fffffffu) : __uint_as_float(~e);
}
__device__ __forceinline__ float coef_of(unsigned p) {
    return __half2float(__ushort_as_half((unsigned short)(p & 0xFFFFu)));
}

// ---------- MEGA: blocks [0,G1BLKS) = gemm1 (raw f16 out); rest = 64-bit packed hist ----------
// packed[d]: high 32 = count, low 32 = sum(ew)*2^24 fixed point. pos[e] = old count.
__global__ void mega1(const float* __restrict__ X, const float* __restrict__ W,
                      __half* __restrict__ Yh, const int* __restrict__ dst,
                      const float* __restrict__ ew,
                      unsigned long long* __restrict__ packed, int* __restrict__ pos) {
    __shared__ float Xl[32][132];
    if (blockIdx.x >= G1BLKS) {
        int e = (blockIdx.x - G1BLKS) * 256 + threadIdx.x;
        if (e < N_EDGES) {
            int d = __builtin_nontemporal_load(&dst[e]);
            float w = __builtin_nontemporal_load(&ew[e]);
            unsigned fix = (unsigned)(w * 16777216.0f);
            unsigned long long old = atomicAdd(&packed[d], 0x100000000ull | (unsigned long long)fix);
            pos[e] = (int)(old >> 32);
        }
        return;
    }
    // ---- gemm1: Yh(f16 pair-major [4][N][32]) = X[N,128] @ W[128,128] (raw) ----
    const int rt = threadIdx.x >> 5;
    const int ct = threadIdx.x & 31;
    const int base = blockIdx.x * 32;
    for (int i = threadIdx.x; i < 32 * 32; i += 256) {
        int rr = i >> 5, cc = (i & 31) << 2;
        int gr = base + rr;
        float4 v = (gr < N_NODES) ? *(const float4*)&X[(size_t)gr * 128 + cc]
                                  : make_float4(0.f, 0.f, 0.f, 0.f);
        Xl[rr][cc] = v.x; Xl[rr][cc + 1] = v.y; Xl[rr][cc + 2] = v.z; Xl[rr][cc + 3] = v.w;
    }
    __syncthreads();
    float acc[4][4] = {};
    for (int k = 0; k < 128; k += 4) {
        float4 a0 = *(const float4*)&Xl[rt * 4 + 0][k];
        float4 a1 = *(const float4*)&Xl[rt * 4 + 1][k];
        float4 a2 = *(const float4*)&Xl[rt * 4 + 2][k];
        float4 a3 = *(const float4*)&Xl[rt * 4 + 3][k];
        float4 w0 = *(const float4*)&W[(size_t)(k + 0) * 128 + ct * 4];
        float4 w1 = *(const float4*)&W[(size_t)(k + 1) * 128 + ct * 4];
        float4 w2 = *(const float4*)&W[(size_t)(k + 2) * 128 + ct * 4];
        float4 w3 = *(const float4*)&W[(size_t)(k + 3) * 128 + ct * 4];
        #define STEP(av, wv)  \
            acc[0][0] += av##0 * wv.x; acc[0][1] += av##0 * wv.y; acc[0][2] += av##0 * wv.z; acc[0][3] += av##0 * wv.w; \
            acc[1][0] += av##1 * wv.x; acc[1][1] += av##1 * wv.y; acc[1][2] += av##1 * wv.z; acc[1][3] += av##1 * wv.w; \
            acc[2][0] += av##2 * wv.x; acc[2][1] += av##2 * wv.y; acc[2][2] += av##2 * wv.z; acc[2][3] += av##2 * wv.w; \
            acc[3][0] += av##3 * wv.x; acc[3][1] += av##3 * wv.y; acc[3][2] += av##3 * wv.z; acc[3][3] += av##3 * wv.w;
        { float ax0=a0.x, ax1=a1.x, ax2=a2.x, ax3=a3.x; STEP(ax, w0) }
        { float ay0=a0.y, ay1=a1.y, ay2=a2.y, ay3=a3.y; STEP(ay, w1) }
        { float az0=a0.z, az1=a1.z, az2=a2.z, az3=a3.z; STEP(az, w2) }
        { float aw0=a0.w, aw1=a1.w, aw2=a2.w, aw3=a3.w; STEP(aw, w3) }
        #undef STEP
    }
    const int pc = ct >> 3;
    const int cw = (ct & 7) * 4;
    for (int i = 0; i < 4; ++i) {
        int gr = base + rt * 4 + i;
        if (gr < N_NODES) {
            ushort4 u;
            u.x = __half_as_ushort(__float2half(acc[i][0]));
            u.y = __half_as_ushort(__float2half(acc[i][1]));
            u.z = __half_as_ushort(__float2half(acc[i][2]));
            u.w = __half_as_ushort(__float2half(acc[i][3]));
            *(ushort4*)&Yh[((size_t)pc * N_NODES + gr) * 32 + cw] = u;
        }
    }
}

// ---------- block sums + dinv (reads packed once) ----------
__global__ void block_sums_dinv(const unsigned long long* __restrict__ packed,
                                int* __restrict__ bsum, float* __restrict__ dinv) {
    __shared__ int s[256];
    int idx = blockIdx.x * 256 + threadIdx.x;
    int c = 0;
    if (idx < N_NODES) {
        unsigned long long p = packed[idx];
        c = (int)(p >> 32);
        dinv[idx] = rsqrtf((float)(unsigned)(p & 0xFFFFFFFFu) * (1.0f / 16777216.0f) + 1.0f);
    }
    s[threadIdx.x] = c;
    __syncthreads();
    for (int o = 128; o; o >>= 1) {
        if (threadIdx.x < o) s[threadIdx.x] += s[threadIdx.x + o];
        __syncthreads();
    }
    if (threadIdx.x == 0) bsum[blockIdx.x] = s[0];
}

__global__ void scan_bsums(const int* __restrict__ bsum, int* __restrict__ boff,
                           int nb, int* __restrict__ row_start_last) {
    __shared__ int s[256];
    int v = (threadIdx.x < nb) ? bsum[threadIdx.x] : 0;
    s[threadIdx.x] = v;
    __syncthreads();
    for (int o = 1; o < 256; o <<= 1) {
        int t = 0;
        if (threadIdx.x >= o) t = s[threadIdx.x - o];
        __syncthreads();
        s[threadIdx.x] += t;
        __syncthreads();
    }
    if (threadIdx.x < nb) boff[threadIdx.x] = s[threadIdx.x] - v;   // exclusive
    if (threadIdx.x == 0) *row_start_last = N_EDGES;
}

__global__ void scan_counts(const unsigned long long* __restrict__ packed,
                            const int* __restrict__ boff, int* __restrict__ row_start) {
    __shared__ int s[256];
    int idx = blockIdx.x * 256 + threadIdx.x;
    int v = (idx < N_NODES) ? (int)(packed[idx] >> 32) : 0;
    s[threadIdx.x] = v;
    __syncthreads();
    for (int o = 1; o < 256; o <<= 1) {
        int t = 0;
        if (threadIdx.x >= o) t = s[threadIdx.x - o];
        __syncthreads();
        s[threadIdx.x] += t;
        __syncthreads();
    }
    if (idx < N_NODES) row_start[idx] = boff[blockIdx.x] + s[threadIdx.x] - v;
}

// ---------- fill CSR: atomic-free, full coef = dinv[s]*ew*dinv[d] as f16 ----------
__global__ void fill_direct(const int* __restrict__ src, const int* __restrict__ dst,
                            const float* __restrict__ ew, const int* __restrict__ pos,
                            const int* __restrict__ row_start, const float* __restrict__ dinv,
                            unsigned* __restrict__ csr) {
    int e = blockIdx.x * 256 + threadIdx.x;
    if (e < N_EDGES) {
        int d = __builtin_nontemporal_load(&dst[e]);
        int s = __builtin_nontemporal_load(&src[e]);
        float w = __builtin_nontemporal_load(&ew[e]);
        int p = __builtin_nontemporal_load(&pos[e]);
        float coef = dinv[s] * w * dinv[d];
        unsigned val = ((unsigned)s << 16) | __half_as_ushort(__float2half(coef));
        __builtin_nontemporal_store(val, &csr[row_start[d] + p]);
    }
}

// ---------- CSR aggregation from raw f16 pair-chunks: 32 lanes/node ----------
// out[n,kg] = relu( sum_e coef_e*xw[src_e] + dinv[n]^2*xw[n] + b[kg] )
template<int NP, bool HOUT>
__global__ void agg_csr_pair(const int* __restrict__ row_start, const unsigned* __restrict__ csr,
                             const __half* __restrict__ xwh, const float* __restrict__ dinv,
                             const float* __restrict__ b, void* __restrict__ outp) {
    constexpr int OUT = NP * 32;
    const int c    = blockIdx.x % NP;
    const int nb   = blockIdx.x / NP;
    const int n    = nb * 8 + (threadIdx.x >> 5);
    const int kk   = threadIdx.x & 15;
    const int half = (threadIdx.x >> 4) & 1;
    if (n >= N_NODES) return;
    const __half* __restrict__ bp = xwh + ((size_t)c * N_NODES) * 32 + 2 * kk;
    const int beg = row_start[n], end = row_start[n + 1];
    float ax = 0.f, ay = 0.f;
    int i = beg + half;
    for (; i + 6 < end; i += 8) {
        unsigned p0 = __builtin_nontemporal_load(&csr[i]);
        unsigned p1 = __builtin_nontemporal_load(&csr[i + 2]);
        unsigned p2 = __builtin_nontemporal_load(&csr[i + 4]);
        unsigned p3 = __builtin_nontemporal_load(&csr[i + 6]);
        float2 f0 = __half22float2(*(const __half2*)(bp + (size_t)(p0 >> 16) * 32));
        float2 f1 = __half22float2(*(const __half2*)(bp + (size_t)(p1 >> 16) * 32));
        float2 f2 = __half22float2(*(const __half2*)(bp + (size_t)(p2 >> 16) * 32));
        float2 f3 = __half22float2(*(const __half2*)(bp + (size_t)(p3 >> 16) * 32));
        float e0 = coef_of(p0), e1 = coef_of(p1), e2 = coef_of(p2), e3 = coef_of(p3);
        ax += e0 * f0.x + e1 * f1.x + e2 * f2.x + e3 * f3.x;
        ay += e0 * f0.y + e1 * f1.y + e2 * f2.y + e3 * f3.y;
    }
    for (; i < end; i += 2) {
        unsigned p = __builtin_nontemporal_load(&csr[i]);
        float2 f = __half22float2(*(const __half2*)(bp + (size_t)(p >> 16) * 32));
        float e = coef_of(p);
        ax += e * f.x; ay += e * f.y;
    }
    ax += __shfl_xor(ax, 16);
    ay += __shfl_xor(ay, 16);
    if (half == 0) {
        float2 sf = __half22float2(*(const __half2*)(bp + (size_t)n * 32));
        float dv = dinv[n];
        float dv2 = dv * dv;
        int kg = c * 32 + 2 * kk;
        float ox = fmaxf(ax + dv2 * sf.x + b[kg], 0.f);
        float oy = fmaxf(ay + dv2 * sf.y + b[kg + 1], 0.f);
        if constexpr (HOUT) {
            __half* o = (__half*)outp;
            *(__half2*)&o[(size_t)n * OUT + kg] = __floats2half2_rn(ox, oy);
        } else {
            float* o = (float*)outp;
            *(float2*)&o[(size_t)n * OUT + kg] = make_float2(ox, oy);
        }
    }
}

// ---------- GEMM2: Yh(raw f16 pair-major [2][N][32]) = Xh(f16 [N,128]) @ W[128,64] ----------
__global__ void gemm2_reg(const __half* __restrict__ Xh, const float* __restrict__ W,
                          __half* __restrict__ Yh, int nrows) {
    __shared__ float Xl[32][132];
    __shared__ float Wl[128][64];
    const int rt = threadIdx.x >> 5;
    const int ct = threadIdx.x & 31;
    const int base = blockIdx.x * 32;
    for (int i = threadIdx.x; i < 32 * 32; i += 256) {
        int rr = i >> 5, cc = (i & 31) << 2;
        int gr = base + rr;
        float2 fa = make_float2(0.f, 0.f), fb = fa;
        if (gr < nrows) {
            const __half2* ph = (const __half2*)&Xh[(size_t)gr * 128 + cc];
            fa = __half22float2(ph[0]);
            fb = __half22float2(ph[1]);
        }
        Xl[rr][cc] = fa.x; Xl[rr][cc + 1] = fa.y; Xl[rr][cc + 2] = fb.x; Xl[rr][cc + 3] = fb.y;
    }
    for (int i = threadIdx.x; i < 128 * 16; i += 256) {
        int kk = i >> 4, cc = (i & 15) << 2;
        *(float4*)&Wl[kk][cc] = *(const float4*)&W[(size_t)kk * 64 + cc];
    }
    float acc[4][2] = {};
    __syncthreads();
    for (int k = 0; k < 128; k += 4) {
        float4 a0 = *(const float4*)&Xl[rt * 4 + 0][k];
        float4 a1 = *(const float4*)&Xl[rt * 4 + 1][k];
        float4 a2 = *(const float4*)&Xl[rt * 4 + 2][k];
        float4 a3 = *(const float4*)&Xl[rt * 4 + 3][k];
        float2 w0 = *(const float2*)&Wl[k + 0][ct * 2];
        float2 w1 = *(const float2*)&Wl[k + 1][ct * 2];
        float2 w2 = *(const float2*)&Wl[k + 2][ct * 2];
        float2 w3 = *(const float2*)&Wl[k + 3][ct * 2];
        acc[0][0] += a0.x * w0.x; acc[0][1] += a0.x * w0.y;
        acc[1][0] += a1.x * w0.x; acc[1][1] += a1.x * w0.y;
        acc[2][0] += a2.x * w0.x; acc[2][1] += a2.x * w0.y;
        acc[3][0] += a3.x * w0.x; acc[3][1] += a3.x * w0.y;
        acc[0][0] += a0.y * w1.x; acc[0][1] += a0.y * w1.y;
        acc[1][0] += a1.y * w1.x; acc[1][1] += a1.y * w1.y;
        acc[2][0] += a2.y * w1.x; acc[2][1] += a2.y * w1.y;
        acc[3][0] += a3.y * w1.x; acc[3][1] += a3.y * w1.y;
        acc[0][0] += a0.z * w2.x; acc[0][1] += a0.z * w2.y;
        acc[1][0] += a1.z * w2.x; acc[1][1] += a1.z * w2.y;
        acc[2][0] += a2.z * w2.x; acc[2][1] += a2.z * w2.y;
        acc[3][0] += a3.z * w2.x; acc[3][1] += a3.z * w2.y;
        acc[0][0] += a0.w * w3.x; acc[0][1] += a0.w * w3.y;
        acc[1][0] += a1.w * w3.x; acc[1][1] += a1.w * w3.y;
        acc[2][0] += a2.w * w3.x; acc[2][1] += a2.w * w3.y;
        acc[3][0] += a3.w * w3.x; acc[3][1] += a3.w * w3.y;
    }
    const int col0 = ct * 2;
    const int pc   = col0 >> 5;
    const int cw   = col0 & 31;
    for (int i = 0; i < 4; ++i) {
        int gr = base + rt * 4 + i;
        if (gr < nrows) {
            __half2 hv = __floats2half2_rn(acc[i][0], acc[i][1]);
            *(__half2*)&Yh[((size_t)pc * nrows + gr) * 32 + cw] = hv;
        }
    }
}

// ---------- gate ----------
__global__ void gate_kernel(const float* __restrict__ x1, const float* __restrict__ gW1,
                            const float* __restrict__ gb1, const float* __restrict__ gW2,
                            const float* __restrict__ gb2, const int* __restrict__ batch,
                            float* __restrict__ g, unsigned* __restrict__ gmax_enc) {
    __shared__ float W1l[64 * 32];
    __shared__ float W2l[32];
    __shared__ float b1l[32];
    for (int i = threadIdx.x; i < 64 * 32; i += 256) W1l[i] = gW1[i];
    if (threadIdx.x < 32) { W2l[threadIdx.x] = gW2[threadIdx.x]; b1l[threadIdx.x] = gb1[threadIdx.x]; }
    __syncthreads();
    const float gb2v = gb2[0];
    int n = blockIdx.x * 256 + threadIdx.x;
    bool act = (n < N_NODES);
    float gv = -1e30f;
    int b = 0;
    if (act) {
        const float* row = x1 + (size_t)n * 64;
        float t[32];
        #pragma unroll
        for (int j = 0; j < 32; ++j) t[j] = b1l[j];
        for (int k = 0; k < 64; ++k) {
            float xv = row[k];
            #pragma unroll
            for (int j = 0; j < 32; ++j) t[j] += xv * W1l[k * 32 + j];
        }
        float a = gb2v;
        #pragma unroll
        for (int j = 0; j < 32; ++j) a += fmaxf(t[j], 0.f) * W2l[j];
        gv = a;
        g[n] = a;
        b = batch[n];
    }
    unsigned long long actm = __ballot(act);
    int b0 = __shfl(b, 0);
    bool uniform = (actm == ~0ull) && (__ballot(b == b0) == ~0ull);
    if (uniform) {
        float m = gv;
        for (int o = 32; o; o >>= 1) m = fmaxf(m, __shfl_xor(m, o));
        if ((threadIdx.x & 63) == 0) atomicMax(&gmax_enc[b0], fenc(m));
    } else if (act) {
        atomicMax(&gmax_enc[b], fenc(gv));
    }
}

// ---------- fused exp+pool: pooledU[g] += ex*x1; den[g] += ex (unnormalized) ----------
__global__ void exp_pool(const float* __restrict__ x1, const float* __restrict__ g,
                         const unsigned* __restrict__ gmax_enc, const int* __restrict__ batch,
                         float* __restrict__ den, float* __restrict__ pooledU) {
    const int L = 32;
    const int f   = threadIdx.x & 63;
    const int grp = threadIdx.x >> 6;
    int chunk = blockIdx.x * 4 + grp;
    int start = chunk * L;
    if (start >= N_NODES) return;
    int end = min(start + L, N_NODES);
    int cur = batch[start];
    float gm = fdec(gmax_enc[cur]);
    float acc = 0.f, accd = 0.f;
    for (int n = start; n < end; ++n) {
        int bb = batch[n];
        if (bb != cur) {
            atomicAdd(&pooledU[cur * 64 + f], acc);
            if (f == 0) atomicAdd(&den[cur], accd);
            acc = 0.f; accd = 0.f; cur = bb; gm = fdec(gmax_enc[cur]);
        }
        float e = expf(g[n] - gm);
        acc += e * x1[(size_t)n * 64 + f];
        if (f == 0) accd += e;
    }
    atomicAdd(&pooledU[cur * 64 + f], acc);
    if (f == 0) atomicAdd(&den[cur], accd);
}

// ---------- head: one block per graph; divides pooledU by den ----------
__global__ void head_kernel(const float* __restrict__ pooledU, const float* __restrict__ den,
                            const float* __restrict__ fcW1, const float* __restrict__ fcb1,
                            const float* __restrict__ fcW2, const float* __restrict__ fcb2,
                            float* __restrict__ out) {
    __shared__ float P[64];
    __shared__ float r0[2], r1[2];
    const int gi = blockIdx.x;
    if (threadIdx.x < 64) P[threadIdx.x] = pooledU[gi * 64 + threadIdx.x] / den[gi];
    __syncthreads();
    const int j = threadIdx.x;                     // 0..127
    float a = fcb1[j];
    #pragma unroll 8
    for (int k = 0; k < 64; ++k) a += P[k] * fcW1[k * 128 + j];
    float h = fmaxf(a, 0.f);
    float p0 = h * fcW2[j * 2 + 0];
    float p1 = h * fcW2[j * 2 + 1];
    for (int o = 32; o; o >>= 1) { p0 += __shfl_xor(p0, o); p1 += __shfl_xor(p1, o); }
    if ((threadIdx.x & 63) == 0) { r0[threadIdx.x >> 6] = p0; r1[threadIdx.x >> 6] = p1; }
    __syncthreads();
    if (threadIdx.x == 0) {
        float l0 = r0[0] + r0[1] + fcb2[0];
        float l1 = r1[0] + r1[1] + fcb2[1];
        float m = fmaxf(l0, l1);
        float lse = m + logf(expf(l0 - m) + expf(l1 - m));
        out[gi * 2 + 0] = l0 - lse;
        out[gi * 2 + 1] = l1 - lse;
    }
}

extern "C" void kernel_launch(void* const* d_in, const int* in_sizes, int n_in,
                              void* d_out, int out_size, void* d_ws, size_t ws_size,
                              hipStream_t stream) {
    const float* x    = (const float*)d_in[0];
    const int*   ei   = (const int*)d_in[1];
    const float* ew   = (const float*)d_in[2];
    const int*   batch= (const int*)d_in[3];
    const float* W1   = (const float*)d_in[4];
    const float* b1   = (const float*)d_in[5];
    const float* W2   = (const float*)d_in[6];
    const float* b2   = (const float*)d_in[7];
    const float* gW1  = (const float*)d_in[8];
    const float* gb1  = (const float*)d_in[9];
    const float* gW2  = (const float*)d_in[10];
    const float* gb2  = (const float*)d_in[11];
    const float* fcW1 = (const float*)d_in[12];
    const float* fcb1 = (const float*)d_in[13];
    const float* fcW2 = (const float*)d_in[14];
    const float* fcb2 = (const float*)d_in[15];
    float* out = (float*)d_out;

    const int* src = ei;
    const int* dst = ei + N_EDGES;

    const int EB = (N_EDGES + 255) / 256;          // 6250
    const int NB = (N_NODES + 255) / 256;          // 196
    const int NBLK8  = (N_NODES + 7) / 8;          // 6250

    // ---- workspace layout (floats) ----
    float* ws = (float*)d_ws;
    __half* xwh  = (__half*)ws;                    // raw f16 pair-major [NP][N][32] (6.4M halves)
    __half* hbuf = (__half*)(ws + 3200000);        // h f16 [N][128] (6.4M halves)
    float*  x1   = ws + 6400000;                   // x1 f32 [N][64]
    size_t off = 9600000;
    unsigned* csr   = (unsigned*)(ws + off); off += 1600000;  // packed (src<<16 | f16 coef)
    int*   pos      = (int*)(ws + off);    off += 1600000;
    int*   row_start= (int*)(ws + off);    off += 50176;
    unsigned long long* packed = (unsigned long long*)(ws + off); off += 100096; // 8B each
    float* dinv     = ws + off;            off += 50176;
    float* g        = ws + off;            off += 50048;
    int*   bsum     = (int*)(ws + off);    off += 256;
    int*   boff     = (int*)(ws + off);    off += 256;
    unsigned* gmax  = (unsigned*)(ws + off); off += 64;
    float* den      = ws + off;            off += 64;
    float* pooled   = ws + off;            off += 4096;

    // ---- memsets (packed hist; gmax|den|pooled contiguous) ----
    hipMemsetAsync(packed, 0, 50048 * sizeof(unsigned long long), stream);
    hipMemsetAsync(gmax, 0, (64 + 64 + 4096) * sizeof(float), stream);

    // ---- phase 1: gemm1 (raw f16) co-dispatched with 64-bit packed hist ----
    mega1<<<G1BLKS + EB, 256, 0, stream>>>(x, W1, xwh, dst, ew, packed, pos);

    // ---- CSR finish ----
    block_sums_dinv<<<NB, 256, 0, stream>>>(packed, bsum, dinv);
    scan_bsums<<<1, 256, 0, stream>>>(bsum, boff, NB, row_start + N_NODES);
    scan_counts<<<NB, 256, 0, stream>>>(packed, boff, row_start);
    fill_direct<<<EB, 256, 0, stream>>>(src, dst, ew, pos, row_start, dinv, csr);

    // ---- conv1 agg -> h (f16 [N][128]) ----
    agg_csr_pair<4, true><<<4 * NBLK8, 256, 0, stream>>>(row_start, csr, xwh, dinv, b1, hbuf);

    // ---- conv2 ----
    gemm2_reg<<<(N_NODES + 31) / 32, 256, 0, stream>>>(hbuf, W2, xwh, N_NODES);
    agg_csr_pair<2, false><<<2 * NBLK8, 256, 0, stream>>>(row_start, csr, xwh, dinv, b2, x1);

    // ---- global attention ----
    gate_kernel<<<NB, 256, 0, stream>>>(x1, gW1, gb1, gW2, gb2, batch, g, gmax);
    {
        int nchunks = (N_NODES + 31) / 32;
        exp_pool<<<(nchunks + 3) / 4, 256, 0, stream>>>(x1, g, gmax, batch, den, pooled);
    }

    // ---- head (64 blocks) ----
    head_kernel<<<N_GRAPHS, 128, 0, stream>>>(pooled, den, fcW1, fcb1, fcW2, fcb2, out);
}

// Round 10
// 341.104 us; speedup vs baseline: 1.1254x; 1.1254x over previous
//
#include <hip/hip_runtime.h>
#include <hip/hip_bf16.h>
#include <hip/hip_fp16.h>

#define N_NODES 50000
#define N_EDGES 1600000
#define N_GRAPHS 64
#define G1BLKS 1563            // ceil(N_NODES/32) gemm1 blocks in mega kernel

// ---------- helpers ----------
__device__ __forceinline__ unsigned fenc(float x) {
    unsigned u = __float_as_uint(x);
    return (u & 0x80000000u) ? ~u : (u | 0x80000000u);
}
__device__ __forceinline__ float fdec(unsigned e) {
    return (e & 0x80000000u) ? __uint_as_float(e & 0x7fffffffu) : __uint_as_float(~e);
}
__device__ __forceinline__ float coef_of(unsigned p) {
    return __half2float(__ushort_as_half((unsigned short)(p & 0xFFFFu)));
}

// ---------- MEGA: blocks [0,G1BLKS) = gemm1 (raw f16 out); rest = 64-bit packed hist ----------
// packed[d]: high 32 = count, low 32 = sum(ew)*2^24 fixed point. pos[e] = old count.
__global__ void mega1(const float* __restrict__ X, const float* __restrict__ W,
                      __half* __restrict__ Yh, const int* __restrict__ dst,
                      const float* __restrict__ ew,
                      unsigned long long* __restrict__ packed, int* __restrict__ pos) {
    __shared__ float Xl[32][132];
    if (blockIdx.x >= G1BLKS) {
        int e = (blockIdx.x - G1BLKS) * 256 + threadIdx.x;
        if (e < N_EDGES) {
            int d = __builtin_nontemporal_load(&dst[e]);
            float w = __builtin_nontemporal_load(&ew[e]);
            unsigned fix = (unsigned)(w * 16777216.0f);
            unsigned long long old = atomicAdd(&packed[d], 0x100000000ull | (unsigned long long)fix);
            pos[e] = (int)(old >> 32);
        }
        return;
    }
    // ---- gemm1: Yh(f16 pair-major [4][N][32]) = X[N,128] @ W[128,128] (raw) ----
    const int rt = threadIdx.x >> 5;
    const int ct = threadIdx.x & 31;
    const int base = blockIdx.x * 32;
    for (int i = threadIdx.x; i < 32 * 32; i += 256) {
        int rr = i >> 5, cc = (i & 31) << 2;
        int gr = base + rr;
        float4 v = (gr < N_NODES) ? *(const float4*)&X[(size_t)gr * 128 + cc]
                                  : make_float4(0.f, 0.f, 0.f, 0.f);
        Xl[rr][cc] = v.x; Xl[rr][cc + 1] = v.y; Xl[rr][cc + 2] = v.z; Xl[rr][cc + 3] = v.w;
    }
    __syncthreads();
    float acc[4][4] = {};
    for (int k = 0; k < 128; k += 4) {
        float4 a0 = *(const float4*)&Xl[rt * 4 + 0][k];
        float4 a1 = *(const float4*)&Xl[rt * 4 + 1][k];
        float4 a2 = *(const float4*)&Xl[rt * 4 + 2][k];
        float4 a3 = *(const float4*)&Xl[rt * 4 + 3][k];
        float4 w0 = *(const float4*)&W[(size_t)(k + 0) * 128 + ct * 4];
        float4 w1 = *(const float4*)&W[(size_t)(k + 1) * 128 + ct * 4];
        float4 w2 = *(const float4*)&W[(size_t)(k + 2) * 128 + ct * 4];
        float4 w3 = *(const float4*)&W[(size_t)(k + 3) * 128 + ct * 4];
        #define STEP(av, wv)  \
            acc[0][0] += av##0 * wv.x; acc[0][1] += av##0 * wv.y; acc[0][2] += av##0 * wv.z; acc[0][3] += av##0 * wv.w; \
            acc[1][0] += av##1 * wv.x; acc[1][1] += av##1 * wv.y; acc[1][2] += av##1 * wv.z; acc[1][3] += av##1 * wv.w; \
            acc[2][0] += av##2 * wv.x; acc[2][1] += av##2 * wv.y; acc[2][2] += av##2 * wv.z; acc[2][3] += av##2 * wv.w; \
            acc[3][0] += av##3 * wv.x; acc[3][1] += av##3 * wv.y; acc[3][2] += av##3 * wv.z; acc[3][3] += av##3 * wv.w;
        { float ax0=a0.x, ax1=a1.x, ax2=a2.x, ax3=a3.x; STEP(ax, w0) }
        { float ay0=a0.y, ay1=a1.y, ay2=a2.y, ay3=a3.y; STEP(ay, w1) }
        { float az0=a0.z, az1=a1.z, az2=a2.z, az3=a3.z; STEP(az, w2) }
        { float aw0=a0.w, aw1=a1.w, aw2=a2.w, aw3=a3.w; STEP(aw, w3) }
        #undef STEP
    }
    const int pc = ct >> 3;
    const int cw = (ct & 7) * 4;
    for (int i = 0; i < 4; ++i) {
        int gr = base + rt * 4 + i;
        if (gr < N_NODES) {
            ushort4 u;
            u.x = __half_as_ushort(__float2half(acc[i][0]));
            u.y = __half_as_ushort(__float2half(acc[i][1]));
            u.z = __half_as_ushort(__float2half(acc[i][2]));
            u.w = __half_as_ushort(__float2half(acc[i][3]));
            *(ushort4*)&Yh[((size_t)pc * N_NODES + gr) * 32 + cw] = u;
        }
    }
}

// ---------- block sums + dinv (reads packed once) ----------
__global__ void block_sums_dinv(const unsigned long long* __restrict__ packed,
                                int* __restrict__ bsum, float* __restrict__ dinv) {
    __shared__ int s[256];
    int idx = blockIdx.x * 256 + threadIdx.x;
    int c = 0;
    if (idx < N_NODES) {
        unsigned long long p = packed[idx];
        c = (int)(p >> 32);
        dinv[idx] = rsqrtf((float)(unsigned)(p & 0xFFFFFFFFu) * (1.0f / 16777216.0f) + 1.0f);
    }
    s[threadIdx.x] = c;
    __syncthreads();
    for (int o = 128; o; o >>= 1) {
        if (threadIdx.x < o) s[threadIdx.x] += s[threadIdx.x + o];
        __syncthreads();
    }
    if (threadIdx.x == 0) bsum[blockIdx.x] = s[0];
}

__global__ void scan_bsums(const int* __restrict__ bsum, int* __restrict__ boff,
                           int nb, int* __restrict__ row_start_last) {
    __shared__ int s[256];
    int v = (threadIdx.x < nb) ? bsum[threadIdx.x] : 0;
    s[threadIdx.x] = v;
    __syncthreads();
    for (int o = 1; o < 256; o <<= 1) {
        int t = 0;
        if (threadIdx.x >= o) t = s[threadIdx.x - o];
        __syncthreads();
        s[threadIdx.x] += t;
        __syncthreads();
    }
    if (threadIdx.x < nb) boff[threadIdx.x] = s[threadIdx.x] - v;   // exclusive
    if (threadIdx.x == 0) *row_start_last = N_EDGES;
}

__global__ void scan_counts(const unsigned long long* __restrict__ packed,
                            const int* __restrict__ boff, int* __restrict__ row_start) {
    __shared__ int s[256];
    int idx = blockIdx.x * 256 + threadIdx.x;
    int v = (idx < N_NODES) ? (int)(packed[idx] >> 32) : 0;
    s[threadIdx.x] = v;
    __syncthreads();
    for (int o = 1; o < 256; o <<= 1) {
        int t = 0;
        if (threadIdx.x >= o) t = s[threadIdx.x - o];
        __syncthreads();
        s[threadIdx.x] += t;
        __syncthreads();
    }
    if (idx < N_NODES) row_start[idx] = boff[blockIdx.x] + s[threadIdx.x] - v;
}

// ---------- fill CSR: atomic-free, full coef = dinv[s]*ew*dinv[d] as f16 ----------
// nt loads on the single-pass edge streams; NORMAL store for csr (it is re-read 6x -> keep in L3)
__global__ void fill_direct(const int* __restrict__ src, const int* __restrict__ dst,
                            const float* __restrict__ ew, const int* __restrict__ pos,
                            const int* __restrict__ row_start, const float* __restrict__ dinv,
                            unsigned* __restrict__ csr) {
    int e = blockIdx.x * 256 + threadIdx.x;
    if (e < N_EDGES) {
        int d = __builtin_nontemporal_load(&dst[e]);
        int s = __builtin_nontemporal_load(&src[e]);
        float w = __builtin_nontemporal_load(&ew[e]);
        int p = __builtin_nontemporal_load(&pos[e]);
        float coef = dinv[s] * w * dinv[d];
        csr[row_start[d] + p] = ((unsigned)s << 16) | __half_as_ushort(__float2half(coef));
    }
}

// ---------- CSR aggregation from raw f16 pair-chunks: 32 lanes/node ----------
// out[n,kg] = relu( sum_e coef_e*xw[src_e] + dinv[n]^2*xw[n] + b[kg] )
template<int NP, bool HOUT>
__global__ void agg_csr_pair(const int* __restrict__ row_start, const unsigned* __restrict__ csr,
                             const __half* __restrict__ xwh, const float* __restrict__ dinv,
                             const float* __restrict__ b, void* __restrict__ outp) {
    constexpr int OUT = NP * 32;
    const int c    = blockIdx.x % NP;
    const int nb   = blockIdx.x / NP;
    const int n    = nb * 8 + (threadIdx.x >> 5);
    const int kk   = threadIdx.x & 15;
    const int half = (threadIdx.x >> 4) & 1;
    if (n >= N_NODES) return;
    const __half* __restrict__ bp = xwh + ((size_t)c * N_NODES) * 32 + 2 * kk;
    const int beg = row_start[n], end = row_start[n + 1];
    float ax = 0.f, ay = 0.f;
    int i = beg + half;
    for (; i + 6 < end; i += 8) {
        unsigned p0 = csr[i],     p1 = csr[i + 2];
        unsigned p2 = csr[i + 4], p3 = csr[i + 6];
        float2 f0 = __half22float2(*(const __half2*)(bp + (size_t)(p0 >> 16) * 32));
        float2 f1 = __half22float2(*(const __half2*)(bp + (size_t)(p1 >> 16) * 32));
        float2 f2 = __half22float2(*(const __half2*)(bp + (size_t)(p2 >> 16) * 32));
        float2 f3 = __half22float2(*(const __half2*)(bp + (size_t)(p3 >> 16) * 32));
        float e0 = coef_of(p0), e1 = coef_of(p1), e2 = coef_of(p2), e3 = coef_of(p3);
        ax += e0 * f0.x + e1 * f1.x + e2 * f2.x + e3 * f3.x;
        ay += e0 * f0.y + e1 * f1.y + e2 * f2.y + e3 * f3.y;
    }
    for (; i < end; i += 2) {
        unsigned p = csr[i];
        float2 f = __half22float2(*(const __half2*)(bp + (size_t)(p >> 16) * 32));
        float e = coef_of(p);
        ax += e * f.x; ay += e * f.y;
    }
    ax += __shfl_xor(ax, 16);
    ay += __shfl_xor(ay, 16);
    if (half == 0) {
        float2 sf = __half22float2(*(const __half2*)(bp + (size_t)n * 32));
        float dv = dinv[n];
        float dv2 = dv * dv;
        int kg = c * 32 + 2 * kk;
        float ox = fmaxf(ax + dv2 * sf.x + b[kg], 0.f);
        float oy = fmaxf(ay + dv2 * sf.y + b[kg + 1], 0.f);
        if constexpr (HOUT) {
            __half* o = (__half*)outp;
            *(__half2*)&o[(size_t)n * OUT + kg] = __floats2half2_rn(ox, oy);
        } else {
            float* o = (float*)outp;
            *(float2*)&o[(size_t)n * OUT + kg] = make_float2(ox, oy);
        }
    }
}

// ---------- GEMM2: Yh(raw f16 pair-major [2][N][32]) = Xh(f16 [N,128]) @ W[128,64] ----------
__global__ void gemm2_reg(const __half* __restrict__ Xh, const float* __restrict__ W,
                          __half* __restrict__ Yh, int nrows) {
    __shared__ float Xl[32][132];
    __shared__ float Wl[128][64];
    const int rt = threadIdx.x >> 5;
    const int ct = threadIdx.x & 31;
    const int base = blockIdx.x * 32;
    for (int i = threadIdx.x; i < 32 * 32; i += 256) {
        int rr = i >> 5, cc = (i & 31) << 2;
        int gr = base + rr;
        float2 fa = make_float2(0.f, 0.f), fb = fa;
        if (gr < nrows) {
            const __half2* ph = (const __half2*)&Xh[(size_t)gr * 128 + cc];
            fa = __half22float2(ph[0]);
            fb = __half22float2(ph[1]);
        }
        Xl[rr][cc] = fa.x; Xl[rr][cc + 1] = fa.y; Xl[rr][cc + 2] = fb.x; Xl[rr][cc + 3] = fb.y;
    }
    for (int i = threadIdx.x; i < 128 * 16; i += 256) {
        int kk = i >> 4, cc = (i & 15) << 2;
        *(float4*)&Wl[kk][cc] = *(const float4*)&W[(size_t)kk * 64 + cc];
    }
    float acc[4][2] = {};
    __syncthreads();
    for (int k = 0; k < 128; k += 4) {
        float4 a0 = *(const float4*)&Xl[rt * 4 + 0][k];
        float4 a1 = *(const float4*)&Xl[rt * 4 + 1][k];
        float4 a2 = *(const float4*)&Xl[rt * 4 + 2][k];
        float4 a3 = *(const float4*)&Xl[rt * 4 + 3][k];
        float2 w0 = *(const float2*)&Wl[k + 0][ct * 2];
        float2 w1 = *(const float2*)&Wl[k + 1][ct * 2];
        float2 w2 = *(const float2*)&Wl[k + 2][ct * 2];
        float2 w3 = *(const float2*)&Wl[k + 3][ct * 2];
        acc[0][0] += a0.x * w0.x; acc[0][1] += a0.x * w0.y;
        acc[1][0] += a1.x * w0.x; acc[1][1] += a1.x * w0.y;
        acc[2][0] += a2.x * w0.x; acc[2][1] += a2.x * w0.y;
        acc[3][0] += a3.x * w0.x; acc[3][1] += a3.x * w0.y;
        acc[0][0] += a0.y * w1.x; acc[0][1] += a0.y * w1.y;
        acc[1][0] += a1.y * w1.x; acc[1][1] += a1.y * w1.y;
        acc[2][0] += a2.y * w1.x; acc[2][1] += a2.y * w1.y;
        acc[3][0] += a3.y * w1.x; acc[3][1] += a3.y * w1.y;
        acc[0][0] += a0.z * w2.x; acc[0][1] += a0.z * w2.y;
        acc[1][0] += a1.z * w2.x; acc[1][1] += a1.z * w2.y;
        acc[2][0] += a2.z * w2.x; acc[2][1] += a2.z * w2.y;
        acc[3][0] += a3.z * w2.x; acc[3][1] += a3.z * w2.y;
        acc[0][0] += a0.w * w3.x; acc[0][1] += a0.w * w3.y;
        acc[1][0] += a1.w * w3.x; acc[1][1] += a1.w * w3.y;
        acc[2][0] += a2.w * w3.x; acc[2][1] += a2.w * w3.y;
        acc[3][0] += a3.w * w3.x; acc[3][1] += a3.w * w3.y;
    }
    const int col0 = ct * 2;
    const int pc   = col0 >> 5;
    const int cw   = col0 & 31;
    for (int i = 0; i < 4; ++i) {
        int gr = base + rt * 4 + i;
        if (gr < nrows) {
            __half2 hv = __floats2half2_rn(acc[i][0], acc[i][1]);
            *(__half2*)&Yh[((size_t)pc * nrows + gr) * 32 + cw] = hv;
        }
    }
}

// ---------- gate ----------
__global__ void gate_kernel(const float* __restrict__ x1, const float* __restrict__ gW1,
                            const float* __restrict__ gb1, const float* __restrict__ gW2,
                            const float* __restrict__ gb2, const int* __restrict__ batch,
                            float* __restrict__ g, unsigned* __restrict__ gmax_enc) {
    __shared__ float W1l[64 * 32];
    __shared__ float W2l[32];
    __shared__ float b1l[32];
    for (int i = threadIdx.x; i < 64 * 32; i += 256) W1l[i] = gW1[i];
    if (threadIdx.x < 32) { W2l[threadIdx.x] = gW2[threadIdx.x]; b1l[threadIdx.x] = gb1[threadIdx.x]; }
    __syncthreads();
    const float gb2v = gb2[0];
    int n = blockIdx.x * 256 + threadIdx.x;
    bool act = (n < N_NODES);
    float gv = -1e30f;
    int b = 0;
    if (act) {
        const float* row = x1 + (size_t)n * 64;
        float t[32];
        #pragma unroll
        for (int j = 0; j < 32; ++j) t[j] = b1l[j];
        for (int k = 0; k < 64; ++k) {
            float xv = row[k];
            #pragma unroll
            for (int j = 0; j < 32; ++j) t[j] += xv * W1l[k * 32 + j];
        }
        float a = gb2v;
        #pragma unroll
        for (int j = 0; j < 32; ++j) a += fmaxf(t[j], 0.f) * W2l[j];
        gv = a;
        g[n] = a;
        b = batch[n];
    }
    unsigned long long actm = __ballot(act);
    int b0 = __shfl(b, 0);
    bool uniform = (actm == ~0ull) && (__ballot(b == b0) == ~0ull);
    if (uniform) {
        float m = gv;
        for (int o = 32; o; o >>= 1) m = fmaxf(m, __shfl_xor(m, o));
        if ((threadIdx.x & 63) == 0) atomicMax(&gmax_enc[b0], fenc(m));
    } else if (act) {
        atomicMax(&gmax_enc[b], fenc(gv));
    }
}

// ---------- fused exp+pool: pooledU[g] += ex*x1; den[g] += ex (unnormalized) ----------
__global__ void exp_pool(const float* __restrict__ x1, const float* __restrict__ g,
                         const unsigned* __restrict__ gmax_enc, const int* __restrict__ batch,
                         float* __restrict__ den, float* __restrict__ pooledU) {
    const int L = 32;
    const int f   = threadIdx.x & 63;
    const int grp = threadIdx.x >> 6;
    int chunk = blockIdx.x * 4 + grp;
    int start = chunk * L;
    if (start >= N_NODES) return;
    int end = min(start + L, N_NODES);
    int cur = batch[start];
    float gm = fdec(gmax_enc[cur]);
    float acc = 0.f, accd = 0.f;
    for (int n = start; n < end; ++n) {
        int bb = batch[n];
        if (bb != cur) {
            atomicAdd(&pooledU[cur * 64 + f], acc);
            if (f == 0) atomicAdd(&den[cur], accd);
            acc = 0.f; accd = 0.f; cur = bb; gm = fdec(gmax_enc[cur]);
        }
        float e = expf(g[n] - gm);
        acc += e * x1[(size_t)n * 64 + f];
        if (f == 0) accd += e;
    }
    atomicAdd(&pooledU[cur * 64 + f], acc);
    if (f == 0) atomicAdd(&den[cur], accd);
}

// ---------- head: one block per graph; divides pooledU by den ----------
__global__ void head_kernel(const float* __restrict__ pooledU, const float* __restrict__ den,
                            const float* __restrict__ fcW1, const float* __restrict__ fcb1,
                            const float* __restrict__ fcW2, const float* __restrict__ fcb2,
                            float* __restrict__ out) {
    __shared__ float P[64];
    __shared__ float r0[2], r1[2];
    const int gi = blockIdx.x;
    if (threadIdx.x < 64) P[threadIdx.x] = pooledU[gi * 64 + threadIdx.x] / den[gi];
    __syncthreads();
    const int j = threadIdx.x;                     // 0..127
    float a = fcb1[j];
    #pragma unroll 8
    for (int k = 0; k < 64; ++k) a += P[k] * fcW1[k * 128 + j];
    float h = fmaxf(a, 0.f);
    float p0 = h * fcW2[j * 2 + 0];
    float p1 = h * fcW2[j * 2 + 1];
    for (int o = 32; o; o >>= 1) { p0 += __shfl_xor(p0, o); p1 += __shfl_xor(p1, o); }
    if ((threadIdx.x & 63) == 0) { r0[threadIdx.x >> 6] = p0; r1[threadIdx.x >> 6] = p1; }
    __syncthreads();
    if (threadIdx.x == 0) {
        float l0 = r0[0] + r0[1] + fcb2[0];
        float l1 = r1[0] + r1[1] + fcb2[1];
        float m = fmaxf(l0, l1);
        float lse = m + logf(expf(l0 - m) + expf(l1 - m));
        out[gi * 2 + 0] = l0 - lse;
        out[gi * 2 + 1] = l1 - lse;
    }
}

extern "C" void kernel_launch(void* const* d_in, const int* in_sizes, int n_in,
                              void* d_out, int out_size, void* d_ws, size_t ws_size,
                              hipStream_t stream) {
    const float* x    = (const float*)d_in[0];
    const int*   ei   = (const int*)d_in[1];
    const float* ew   = (const float*)d_in[2];
    const int*   batch= (const int*)d_in[3];
    const float* W1   = (const float*)d_in[4];
    const float* b1   = (const float*)d_in[5];
    const float* W2   = (const float*)d_in[6];
    const float* b2   = (const float*)d_in[7];
    const float* gW1  = (const float*)d_in[8];
    const float* gb1  = (const float*)d_in[9];
    const float* gW2  = (const float*)d_in[10];
    const float* gb2  = (const float*)d_in[11];
    const float* fcW1 = (const float*)d_in[12];
    const float* fcb1 = (const float*)d_in[13];
    const float* fcW2 = (const float*)d_in[14];
    const float* fcb2 = (const float*)d_in[15];
    float* out = (float*)d_out;

    const int* src = ei;
    const int* dst = ei + N_EDGES;

    const int EB = (N_EDGES + 255) / 256;          // 6250
    const int NB = (N_NODES + 255) / 256;          // 196
    const int NBLK8  = (N_NODES + 7) / 8;          // 6250

    // ---- workspace layout (floats) ----
    float* ws = (float*)d_ws;
    __half* xwh  = (__half*)ws;                    // raw f16 pair-major [NP][N][32] (6.4M halves)
    __half* hbuf = (__half*)(ws + 3200000);        // h f16 [N][128] (6.4M halves)
    float*  x1   = ws + 6400000;                   // x1 f32 [N][64]
    size_t off = 9600000;
    unsigned* csr   = (unsigned*)(ws + off); off += 1600000;  // packed (src<<16 | f16 coef)
    int*   pos      = (int*)(ws + off);    off += 1600000;
    int*   row_start= (int*)(ws + off);    off += 50176;
    unsigned long long* packed = (unsigned long long*)(ws + off); off += 100096; // 8B each
    float* dinv     = ws + off;            off += 50176;
    float* g        = ws + off;            off += 50048;
    int*   bsum     = (int*)(ws + off);    off += 256;
    int*   boff     = (int*)(ws + off);    off += 256;
    unsigned* gmax  = (unsigned*)(ws + off); off += 64;
    float* den      = ws + off;            off += 64;
    float* pooled   = ws + off;            off += 4096;

    // ---- memsets (packed hist; gmax|den|pooled contiguous) ----
    hipMemsetAsync(packed, 0, 50048 * sizeof(unsigned long long), stream);
    hipMemsetAsync(gmax, 0, (64 + 64 + 4096) * sizeof(float), stream);

    // ---- phase 1: gemm1 (raw f16) co-dispatched with 64-bit packed hist ----
    mega1<<<G1BLKS + EB, 256, 0, stream>>>(x, W1, xwh, dst, ew, packed, pos);

    // ---- CSR finish ----
    block_sums_dinv<<<NB, 256, 0, stream>>>(packed, bsum, dinv);
    scan_bsums<<<1, 256, 0, stream>>>(bsum, boff, NB, row_start + N_NODES);
    scan_counts<<<NB, 256, 0, stream>>>(packed, boff, row_start);
    fill_direct<<<EB, 256, 0, stream>>>(src, dst, ew, pos, row_start, dinv, csr);

    // ---- conv1 agg -> h (f16 [N][128]) ----
    agg_csr_pair<4, true><<<4 * NBLK8, 256, 0, stream>>>(row_start, csr, xwh, dinv, b1, hbuf);

    // ---- conv2 ----
    gemm2_reg<<<(N_NODES + 31) / 32, 256, 0, stream>>>(hbuf, W2, xwh, N_NODES);
    agg_csr_pair<2, false><<<2 * NBLK8, 256, 0, stream>>>(row_start, csr, xwh, dinv, b2, x1);

    // ---- global attention ----
    gate_kernel<<<NB, 256, 0, stream>>>(x1, gW1, gb1, gW2, gb2, batch, g, gmax);
    {
        int nchunks = (N_NODES + 31) / 32;
        exp_pool<<<(nchunks + 3) / 4, 256, 0, stream>>>(x1, g, gmax, batch, den, pooled);
    }

    // ---- head (64 blocks) ----
    head_kernel<<<N_GRAPHS, 128, 0, stream>>>(pooled, den, fcW1, fcb1, fcW2, fcb2, out);
}

// Round 11
// 341.072 us; speedup vs baseline: 1.1255x; 1.0001x over previous
//
#include <hip/hip_runtime.h>
#include <hip/hip_bf16.h>
#include <hip/hip_fp16.h>

#define N_NODES 50000
#define N_EDGES 1600000
#define N_GRAPHS 64
#define G1BLKS 1563            // ceil(N_NODES/32) gemm1 blocks in mega kernel

// ---------- helpers ----------
__device__ __forceinline__ float coef_of(unsigned p) {
    return __half2float(__ushort_as_half((unsigned short)(p & 0xFFFFu)));
}

// ---------- MEGA: blocks [0,G1BLKS) = gemm1 (raw f16 out); rest = 64-bit packed hist ----------
// packed[d]: high 32 = count, low 32 = sum(ew)*2^24 fixed point. pos16[e] = old count.
__global__ void mega1(const float* __restrict__ X, const float* __restrict__ W,
                      __half* __restrict__ Yh, const int* __restrict__ dst,
                      const float* __restrict__ ew,
                      unsigned long long* __restrict__ packed,
                      unsigned short* __restrict__ pos16) {
    __shared__ float Xl[32][132];
    if (blockIdx.x >= G1BLKS) {
        int e = (blockIdx.x - G1BLKS) * 256 + threadIdx.x;
        if (e < N_EDGES) {
            int d = __builtin_nontemporal_load(&dst[e]);
            float w = __builtin_nontemporal_load(&ew[e]);
            unsigned fix = (unsigned)(w * 16777216.0f);
            unsigned long long old = atomicAdd(&packed[d], 0x100000000ull | (unsigned long long)fix);
            pos16[e] = (unsigned short)(old >> 32);
        }
        return;
    }
    // ---- gemm1: Yh(f16 pair-major [4][N][32]) = X[N,128] @ W[128,128] (raw) ----
    const int rt = threadIdx.x >> 5;
    const int ct = threadIdx.x & 31;
    const int base = blockIdx.x * 32;
    for (int i = threadIdx.x; i < 32 * 32; i += 256) {
        int rr = i >> 5, cc = (i & 31) << 2;
        int gr = base + rr;
        float4 v = (gr < N_NODES) ? *(const float4*)&X[(size_t)gr * 128 + cc]
                                  : make_float4(0.f, 0.f, 0.f, 0.f);
        Xl[rr][cc] = v.x; Xl[rr][cc + 1] = v.y; Xl[rr][cc + 2] = v.z; Xl[rr][cc + 3] = v.w;
    }
    __syncthreads();
    float acc[4][4] = {};
    for (int k = 0; k < 128; k += 4) {
        float4 a0 = *(const float4*)&Xl[rt * 4 + 0][k];
        float4 a1 = *(const float4*)&Xl[rt * 4 + 1][k];
        float4 a2 = *(const float4*)&Xl[rt * 4 + 2][k];
        float4 a3 = *(const float4*)&Xl[rt * 4 + 3][k];
        float4 w0 = *(const float4*)&W[(size_t)(k + 0) * 128 + ct * 4];
        float4 w1 = *(const float4*)&W[(size_t)(k + 1) * 128 + ct * 4];
        float4 w2 = *(const float4*)&W[(size_t)(k + 2) * 128 + ct * 4];
        float4 w3 = *(const float4*)&W[(size_t)(k + 3) * 128 + ct * 4];
        #define STEP(av, wv)  \
            acc[0][0] += av##0 * wv.x; acc[0][1] += av##0 * wv.y; acc[0][2] += av##0 * wv.z; acc[0][3] += av##0 * wv.w; \
            acc[1][0] += av##1 * wv.x; acc[1][1] += av##1 * wv.y; acc[1][2] += av##1 * wv.z; acc[1][3] += av##1 * wv.w; \
            acc[2][0] += av##2 * wv.x; acc[2][1] += av##2 * wv.y; acc[2][2] += av##2 * wv.z; acc[2][3] += av##2 * wv.w; \
            acc[3][0] += av##3 * wv.x; acc[3][1] += av##3 * wv.y; acc[3][2] += av##3 * wv.z; acc[3][3] += av##3 * wv.w;
        { float ax0=a0.x, ax1=a1.x, ax2=a2.x, ax3=a3.x; STEP(ax, w0) }
        { float ay0=a0.y, ay1=a1.y, ay2=a2.y, ay3=a3.y; STEP(ay, w1) }
        { float az0=a0.z, az1=a1.z, az2=a2.z, az3=a3.z; STEP(az, w2) }
        { float aw0=a0.w, aw1=a1.w, aw2=a2.w, aw3=a3.w; STEP(aw, w3) }
        #undef STEP
    }
    const int pc = ct >> 3;
    const int cw = (ct & 7) * 4;
    for (int i = 0; i < 4; ++i) {
        int gr = base + rt * 4 + i;
        if (gr < N_NODES) {
            ushort4 u;
            u.x = __half_as_ushort(__float2half(acc[i][0]));
            u.y = __half_as_ushort(__float2half(acc[i][1]));
            u.z = __half_as_ushort(__float2half(acc[i][2]));
            u.w = __half_as_ushort(__float2half(acc[i][3]));
            *(ushort4*)&Yh[((size_t)pc * N_NODES + gr) * 32 + cw] = u;
        }
    }
}

// ---------- block sums + dinv (reads packed once) ----------
__global__ void block_sums_dinv(const unsigned long long* __restrict__ packed,
                                int* __restrict__ bsum, float* __restrict__ dinv) {
    __shared__ int s[256];
    int idx = blockIdx.x * 256 + threadIdx.x;
    int c = 0;
    if (idx < N_NODES) {
        unsigned long long p = packed[idx];
        c = (int)(p >> 32);
        dinv[idx] = rsqrtf((float)(unsigned)(p & 0xFFFFFFFFu) * (1.0f / 16777216.0f) + 1.0f);
    }
    s[threadIdx.x] = c;
    __syncthreads();
    for (int o = 128; o; o >>= 1) {
        if (threadIdx.x < o) s[threadIdx.x] += s[threadIdx.x + o];
        __syncthreads();
    }
    if (threadIdx.x == 0) bsum[blockIdx.x] = s[0];
}

__global__ void scan_bsums(const int* __restrict__ bsum, int* __restrict__ boff,
                           int nb, int* __restrict__ row_start_last) {
    __shared__ int s[256];
    int v = (threadIdx.x < nb) ? bsum[threadIdx.x] : 0;
    s[threadIdx.x] = v;
    __syncthreads();
    for (int o = 1; o < 256; o <<= 1) {
        int t = 0;
        if (threadIdx.x >= o) t = s[threadIdx.x - o];
        __syncthreads();
        s[threadIdx.x] += t;
        __syncthreads();
    }
    if (threadIdx.x < nb) boff[threadIdx.x] = s[threadIdx.x] - v;   // exclusive
    if (threadIdx.x == 0) *row_start_last = N_EDGES;
}

__global__ void scan_counts(const unsigned long long* __restrict__ packed,
                            const int* __restrict__ boff, int* __restrict__ row_start) {
    __shared__ int s[256];
    int idx = blockIdx.x * 256 + threadIdx.x;
    int v = (idx < N_NODES) ? (int)(packed[idx] >> 32) : 0;
    s[threadIdx.x] = v;
    __syncthreads();
    for (int o = 1; o < 256; o <<= 1) {
        int t = 0;
        if (threadIdx.x >= o) t = s[threadIdx.x - o];
        __syncthreads();
        s[threadIdx.x] += t;
        __syncthreads();
    }
    if (idx < N_NODES) row_start[idx] = boff[blockIdx.x] + s[threadIdx.x] - v;
}

// ---------- fill CSR: atomic-free, full coef = dinv[s]*ew*dinv[d] as f16 ----------
// nt loads on single-pass streams; normal store for csr (re-read 6x -> keep cached)
__global__ void fill_direct(const int* __restrict__ src, const int* __restrict__ dst,
                            const float* __restrict__ ew, const unsigned short* __restrict__ pos16,
                            const int* __restrict__ row_start, const float* __restrict__ dinv,
                            unsigned* __restrict__ csr) {
    int e = blockIdx.x * 256 + threadIdx.x;
    if (e < N_EDGES) {
        int d = __builtin_nontemporal_load(&dst[e]);
        int s = __builtin_nontemporal_load(&src[e]);
        float w = __builtin_nontemporal_load(&ew[e]);
        int p = (int)__builtin_nontemporal_load(&pos16[e]);
        float coef = dinv[s] * w * dinv[d];
        csr[row_start[d] + p] = ((unsigned)s << 16) | __half_as_ushort(__float2half(coef));
    }
}

// ---------- CSR aggregation: 64 lanes/node (16 feat-pairs x 4 edge-quarters) ----------
// out[n,kg] = relu( sum_e coef_e*xw[src_e] + dinv[n]^2*xw[n] + b[kg] )
template<int NP, bool HOUT>
__global__ void agg_csr_pair(const int* __restrict__ row_start, const unsigned* __restrict__ csr,
                             const __half* __restrict__ xwh, const float* __restrict__ dinv,
                             const float* __restrict__ b, void* __restrict__ outp) {
    constexpr int OUT = NP * 32;
    const int c  = blockIdx.x % NP;
    const int nb = blockIdx.x / NP;
    const int n  = nb * 4 + (threadIdx.x >> 6);     // 4 nodes/block, one wave each
    const int kk = threadIdx.x & 15;                // feature pair
    const int q  = (threadIdx.x >> 4) & 3;          // edge quarter
    if (n >= N_NODES) return;
    const __half* __restrict__ bp = xwh + ((size_t)c * N_NODES) * 32 + 2 * kk;
    const int beg = row_start[n], end = row_start[n + 1];
    float ax = 0.f, ay = 0.f;
    int i = beg + q;
    for (; i + 12 < end; i += 16) {                 // this quarter: i, i+4, i+8, i+12
        unsigned p0 = csr[i],     p1 = csr[i + 4];
        unsigned p2 = csr[i + 8], p3 = csr[i + 12];
        float2 f0 = __half22float2(*(const __half2*)(bp + (size_t)(p0 >> 16) * 32));
        float2 f1 = __half22float2(*(const __half2*)(bp + (size_t)(p1 >> 16) * 32));
        float2 f2 = __half22float2(*(const __half2*)(bp + (size_t)(p2 >> 16) * 32));
        float2 f3 = __half22float2(*(const __half2*)(bp + (size_t)(p3 >> 16) * 32));
        float e0 = coef_of(p0), e1 = coef_of(p1), e2 = coef_of(p2), e3 = coef_of(p3);
        ax += e0 * f0.x + e1 * f1.x + e2 * f2.x + e3 * f3.x;
        ay += e0 * f0.y + e1 * f1.y + e2 * f2.y + e3 * f3.y;
    }
    for (; i < end; i += 4) {
        unsigned p = csr[i];
        float2 f = __half22float2(*(const __half2*)(bp + (size_t)(p >> 16) * 32));
        float e = coef_of(p);
        ax += e * f.x; ay += e * f.y;
    }
    ax += __shfl_xor(ax, 16);  ay += __shfl_xor(ay, 16);
    ax += __shfl_xor(ax, 32);  ay += __shfl_xor(ay, 32);
    if (q == 0) {
        float2 sf = __half22float2(*(const __half2*)(bp + (size_t)n * 32));
        float dv = dinv[n];
        float dv2 = dv * dv;
        int kg = c * 32 + 2 * kk;
        float ox = fmaxf(ax + dv2 * sf.x + b[kg], 0.f);
        float oy = fmaxf(ay + dv2 * sf.y + b[kg + 1], 0.f);
        if constexpr (HOUT) {
            __half* o = (__half*)outp;
            *(__half2*)&o[(size_t)n * OUT + kg] = __floats2half2_rn(ox, oy);
        } else {
            float* o = (float*)outp;
            *(float2*)&o[(size_t)n * OUT + kg] = make_float2(ox, oy);
        }
    }
}

// ---------- GEMM2: Yh(raw f16 pair-major [2][N][32]) = Xh(f16 [N,128]) @ W[128,64] ----------
__global__ void gemm2_reg(const __half* __restrict__ Xh, const float* __restrict__ W,
                          __half* __restrict__ Yh, int nrows) {
    __shared__ float Xl[32][132];
    __shared__ float Wl[128][64];
    const int rt = threadIdx.x >> 5;
    const int ct = threadIdx.x & 31;
    const int base = blockIdx.x * 32;
    for (int i = threadIdx.x; i < 32 * 32; i += 256) {
        int rr = i >> 5, cc = (i & 31) << 2;
        int gr = base + rr;
        float2 fa = make_float2(0.f, 0.f), fb = fa;
        if (gr < nrows) {
            const __half2* ph = (const __half2*)&Xh[(size_t)gr * 128 + cc];
            fa = __half22float2(ph[0]);
            fb = __half22float2(ph[1]);
        }
        Xl[rr][cc] = fa.x; Xl[rr][cc + 1] = fa.y; Xl[rr][cc + 2] = fb.x; Xl[rr][cc + 3] = fb.y;
    }
    for (int i = threadIdx.x; i < 128 * 16; i += 256) {
        int kk = i >> 4, cc = (i & 15) << 2;
        *(float4*)&Wl[kk][cc] = *(const float4*)&W[(size_t)kk * 64 + cc];
    }
    float acc[4][2] = {};
    __syncthreads();
    for (int k = 0; k < 128; k += 4) {
        float4 a0 = *(const float4*)&Xl[rt * 4 + 0][k];
        float4 a1 = *(const float4*)&Xl[rt * 4 + 1][k];
        float4 a2 = *(const float4*)&Xl[rt * 4 + 2][k];
        float4 a3 = *(const float4*)&Xl[rt * 4 + 3][k];
        float2 w0 = *(const float2*)&Wl[k + 0][ct * 2];
        float2 w1 = *(const float2*)&Wl[k + 1][ct * 2];
        float2 w2 = *(const float2*)&Wl[k + 2][ct * 2];
        float2 w3 = *(const float2*)&Wl[k + 3][ct * 2];
        acc[0][0] += a0.x * w0.x; acc[0][1] += a0.x * w0.y;
        acc[1][0] += a1.x * w0.x; acc[1][1] += a1.x * w0.y;
        acc[2][0] += a2.x * w0.x; acc[2][1] += a2.x * w0.y;
        acc[3][0] += a3.x * w0.x; acc[3][1] += a3.x * w0.y;
        acc[0][0] += a0.y * w1.x; acc[0][1] += a0.y * w1.y;
        acc[1][0] += a1.y * w1.x; acc[1][1] += a1.y * w1.y;
        acc[2][0] += a2.y * w1.x; acc[2][1] += a2.y * w1.y;
        acc[3][0] += a3.y * w1.x; acc[3][1] += a3.y * w1.y;
        acc[0][0] += a0.z * w2.x; acc[0][1] += a0.z * w2.y;
        acc[1][0] += a1.z * w2.x; acc[1][1] += a1.z * w2.y;
        acc[2][0] += a2.z * w2.x; acc[2][1] += a2.z * w2.y;
        acc[3][0] += a3.z * w2.x; acc[3][1] += a3.z * w2.y;
        acc[0][0] += a0.w * w3.x; acc[0][1] += a0.w * w3.y;
        acc[1][0] += a1.w * w3.x; acc[1][1] += a1.w * w3.y;
        acc[2][0] += a2.w * w3.x; acc[2][1] += a2.w * w3.y;
        acc[3][0] += a3.w * w3.x; acc[3][1] += a3.w * w3.y;
    }
    const int col0 = ct * 2;
    const int pc   = col0 >> 5;
    const int cw   = col0 & 31;
    for (int i = 0; i < 4; ++i) {
        int gr = base + rt * 4 + i;
        if (gr < nrows) {
            __half2 hv = __floats2half2_rn(acc[i][0], acc[i][1]);
            *(__half2*)&Yh[((size_t)pc * nrows + gr) * 32 + cw] = hv;
        }
    }
}

// ---------- fused gate + exp + pool (no max-subtraction: |g| ~ O(1), exp safe) ----------
// phase1: 1 thread/node computes e = exp(gate(x1_row)) -> LDS
// phase2: 4 groups x 64 threads run-length pool 64 nodes each into pooledU/den
__global__ void gate_pool(const float* __restrict__ x1, const float* __restrict__ gW1,
                          const float* __restrict__ gb1, const float* __restrict__ gW2,
                          const float* __restrict__ gb2, const int* __restrict__ batch,
                          float* __restrict__ den, float* __restrict__ pooledU) {
    __shared__ float W1l[64 * 32];
    __shared__ float W2l[32];
    __shared__ float b1l[32];
    __shared__ float el[256];
    for (int i = threadIdx.x; i < 64 * 32; i += 256) W1l[i] = gW1[i];
    if (threadIdx.x < 32) { W2l[threadIdx.x] = gW2[threadIdx.x]; b1l[threadIdx.x] = gb1[threadIdx.x]; }
    __syncthreads();
    const float gb2v = gb2[0];
    const int n0 = blockIdx.x * 256;
    const int n = n0 + threadIdx.x;
    float ev = 0.f;
    if (n < N_NODES) {
        const float* row = x1 + (size_t)n * 64;
        float t[32];
        #pragma unroll
        for (int j = 0; j < 32; ++j) t[j] = b1l[j];
        for (int k = 0; k < 64; ++k) {
            float xv = row[k];
            #pragma unroll
            for (int j = 0; j < 32; ++j) t[j] += xv * W1l[k * 32 + j];
        }
        float a = gb2v;
        #pragma unroll
        for (int j = 0; j < 32; ++j) a += fmaxf(t[j], 0.f) * W2l[j];
        ev = expf(a);
    }
    el[threadIdx.x] = ev;
    __syncthreads();
    const int f   = threadIdx.x & 63;
    const int grp = threadIdx.x >> 6;
    int start = n0 + grp * 64;
    if (start >= N_NODES) return;
    int end = min(start + 64, N_NODES);
    int cur = batch[start];
    float acc = 0.f, accd = 0.f;
    for (int m = start; m < end; ++m) {
        int bb = batch[m];
        if (bb != cur) {
            atomicAdd(&pooledU[cur * 64 + f], acc);
            if (f == 0) atomicAdd(&den[cur], accd);
            acc = 0.f; accd = 0.f; cur = bb;
        }
        float e = el[m - n0];
        acc += e * x1[(size_t)m * 64 + f];
        if (f == 0) accd += e;
    }
    atomicAdd(&pooledU[cur * 64 + f], acc);
    if (f == 0) atomicAdd(&den[cur], accd);
}

// ---------- head: one block per graph; divides pooledU by den ----------
__global__ void head_kernel(const float* __restrict__ pooledU, const float* __restrict__ den,
                            const float* __restrict__ fcW1, const float* __restrict__ fcb1,
                            const float* __restrict__ fcW2, const float* __restrict__ fcb2,
                            float* __restrict__ out) {
    __shared__ float P[64];
    __shared__ float r0[2], r1[2];
    const int gi = blockIdx.x;
    if (threadIdx.x < 64) P[threadIdx.x] = pooledU[gi * 64 + threadIdx.x] / den[gi];
    __syncthreads();
    const int j = threadIdx.x;                     // 0..127
    float a = fcb1[j];
    #pragma unroll 8
    for (int k = 0; k < 64; ++k) a += P[k] * fcW1[k * 128 + j];
    float h = fmaxf(a, 0.f);
    float p0 = h * fcW2[j * 2 + 0];
    float p1 = h * fcW2[j * 2 + 1];
    for (int o = 32; o; o >>= 1) { p0 += __shfl_xor(p0, o); p1 += __shfl_xor(p1, o); }
    if ((threadIdx.x & 63) == 0) { r0[threadIdx.x >> 6] = p0; r1[threadIdx.x >> 6] = p1; }
    __syncthreads();
    if (threadIdx.x == 0) {
        float l0 = r0[0] + r0[1] + fcb2[0];
        float l1 = r1[0] + r1[1] + fcb2[1];
        float m = fmaxf(l0, l1);
        float lse = m + logf(expf(l0 - m) + expf(l1 - m));
        out[gi * 2 + 0] = l0 - lse;
        out[gi * 2 + 1] = l1 - lse;
    }
}

extern "C" void kernel_launch(void* const* d_in, const int* in_sizes, int n_in,
                              void* d_out, int out_size, void* d_ws, size_t ws_size,
                              hipStream_t stream) {
    const float* x    = (const float*)d_in[0];
    const int*   ei   = (const int*)d_in[1];
    const float* ew   = (const float*)d_in[2];
    const int*   batch= (const int*)d_in[3];
    const float* W1   = (const float*)d_in[4];
    const float* b1   = (const float*)d_in[5];
    const float* W2   = (const float*)d_in[6];
    const float* b2   = (const float*)d_in[7];
    const float* gW1  = (const float*)d_in[8];
    const float* gb1  = (const float*)d_in[9];
    const float* gW2  = (const float*)d_in[10];
    const float* gb2  = (const float*)d_in[11];
    const float* fcW1 = (const float*)d_in[12];
    const float* fcb1 = (const float*)d_in[13];
    const float* fcW2 = (const float*)d_in[14];
    const float* fcb2 = (const float*)d_in[15];
    float* out = (float*)d_out;

    const int* src = ei;
    const int* dst = ei + N_EDGES;

    const int EB = (N_EDGES + 255) / 256;          // 6250
    const int NB = (N_NODES + 255) / 256;          // 196
    const int NBLK4 = (N_NODES + 3) / 4;           // 12500

    // ---- workspace layout (floats) ----
    float* ws = (float*)d_ws;
    __half* xwh  = (__half*)ws;                    // raw f16 pair-major [NP][N][32] (6.4M halves)
    __half* hbuf = (__half*)(ws + 3200000);        // h f16 [N][128] (6.4M halves)
    float*  x1   = ws + 6400000;                   // x1 f32 [N][64]
    size_t off = 9600000;
    unsigned* csr   = (unsigned*)(ws + off); off += 1600000;  // packed (src<<16 | f16 coef)
    unsigned short* pos16 = (unsigned short*)(ws + off); off += 800000;
    int*   row_start= (int*)(ws + off);    off += 50176;
    unsigned long long* packed = (unsigned long long*)(ws + off); off += 100096; // 8B each
    float* dinv     = ws + off;            off += 50176;
    int*   bsum     = (int*)(ws + off);    off += 256;
    int*   boff     = (int*)(ws + off);    off += 256;
    float* den      = ws + off;            off += 64;
    float* pooled   = ws + off;            off += 4096;

    // ---- memsets ----
    hipMemsetAsync(packed, 0, 50048 * sizeof(unsigned long long), stream);
    hipMemsetAsync(den, 0, (64 + 4096) * sizeof(float), stream);

    // ---- phase 1: gemm1 (raw f16) co-dispatched with 64-bit packed hist ----
    mega1<<<G1BLKS + EB, 256, 0, stream>>>(x, W1, xwh, dst, ew, packed, pos16);

    // ---- CSR finish ----
    block_sums_dinv<<<NB, 256, 0, stream>>>(packed, bsum, dinv);
    scan_bsums<<<1, 256, 0, stream>>>(bsum, boff, NB, row_start + N_NODES);
    scan_counts<<<NB, 256, 0, stream>>>(packed, boff, row_start);
    fill_direct<<<EB, 256, 0, stream>>>(src, dst, ew, pos16, row_start, dinv, csr);

    // ---- conv1 agg -> h (f16 [N][128]) ----
    agg_csr_pair<4, true><<<4 * NBLK4, 256, 0, stream>>>(row_start, csr, xwh, dinv, b1, hbuf);

    // ---- conv2 ----
    gemm2_reg<<<(N_NODES + 31) / 32, 256, 0, stream>>>(hbuf, W2, xwh, N_NODES);
    agg_csr_pair<2, false><<<2 * NBLK4, 256, 0, stream>>>(row_start, csr, xwh, dinv, b2, x1);

    // ---- fused gate + exp + pool ----
    gate_pool<<<NB, 256, 0, stream>>>(x1, gW1, gb1, gW2, gb2, batch, den, pooled);

    // ---- head (64 blocks) ----
    head_kernel<<<N_GRAPHS, 128, 0, stream>>>(pooled, den, fcW1, fcb1, fcW2, fcb2, out);
}

// Round 12
// 337.077 us; speedup vs baseline: 1.1389x; 1.0119x over previous
//
#include <hip/hip_runtime.h>
#include <hip/hip_bf16.h>
#include <hip/hip_fp16.h>

#define N_NODES 50000
#define N_EDGES 1600000
#define N_GRAPHS 64
#define G1BLKS 1563            // ceil(N_NODES/32) gemm1 blocks in mega kernel
#define NSH 8                  // histogram shards (≈ XCDs)
#define SH_STRIDE 50048        // per-shard stride (≥ N_NODES, 64B aligned)

// ---------- helpers ----------
__device__ __forceinline__ float coef_of(unsigned p) {
    return __half2float(__ushort_as_half((unsigned short)(p & 0xFFFFu)));
}

// ---------- MEGA: blocks [0,G1BLKS) = gemm1 (raw f16 out); rest = sharded packed hist ----------
// packed8[s][d]: high 32 = count, low 32 = sum(ew)*2^24 fixed point.
// pos16[e] = (shard<<12) | old_count_within_shard.
__global__ void mega1(const float* __restrict__ X, const float* __restrict__ W,
                      __half* __restrict__ Yh, const int* __restrict__ dst,
                      const float* __restrict__ ew,
                      unsigned long long* __restrict__ packed8,
                      unsigned short* __restrict__ pos16) {
    __shared__ float Xl[32][132];
    if (blockIdx.x >= G1BLKS) {
        const int sh = blockIdx.x & (NSH - 1);     // ≈ physical XCD under round-robin dispatch
        unsigned long long* __restrict__ pk = packed8 + (size_t)sh * SH_STRIDE;
        int e = (blockIdx.x - G1BLKS) * 256 + threadIdx.x;
        if (e < N_EDGES) {
            int d = __builtin_nontemporal_load(&dst[e]);
            float w = __builtin_nontemporal_load(&ew[e]);
            unsigned fix = (unsigned)(w * 16777216.0f);
            unsigned long long old = atomicAdd(&pk[d], 0x100000000ull | (unsigned long long)fix);
            pos16[e] = (unsigned short)((sh << 12) | (unsigned)(old >> 32));
        }
        return;
    }
    // ---- gemm1: Yh(f16 pair-major [4][N][32]) = X[N,128] @ W[128,128] (raw) ----
    const int rt = threadIdx.x >> 5;
    const int ct = threadIdx.x & 31;
    const int base = blockIdx.x * 32;
    for (int i = threadIdx.x; i < 32 * 32; i += 256) {
        int rr = i >> 5, cc = (i & 31) << 2;
        int gr = base + rr;
        float4 v = (gr < N_NODES) ? *(const float4*)&X[(size_t)gr * 128 + cc]
                                  : make_float4(0.f, 0.f, 0.f, 0.f);
        Xl[rr][cc] = v.x; Xl[rr][cc + 1] = v.y; Xl[rr][cc + 2] = v.z; Xl[rr][cc + 3] = v.w;
    }
    __syncthreads();
    float acc[4][4] = {};
    for (int k = 0; k < 128; k += 4) {
        float4 a0 = *(const float4*)&Xl[rt * 4 + 0][k];
        float4 a1 = *(const float4*)&Xl[rt * 4 + 1][k];
        float4 a2 = *(const float4*)&Xl[rt * 4 + 2][k];
        float4 a3 = *(const float4*)&Xl[rt * 4 + 3][k];
        float4 w0 = *(const float4*)&W[(size_t)(k + 0) * 128 + ct * 4];
        float4 w1 = *(const float4*)&W[(size_t)(k + 1) * 128 + ct * 4];
        float4 w2 = *(const float4*)&W[(size_t)(k + 2) * 128 + ct * 4];
        float4 w3 = *(const float4*)&W[(size_t)(k + 3) * 128 + ct * 4];
        #define STEP(av, wv)  \
            acc[0][0] += av##0 * wv.x; acc[0][1] += av##0 * wv.y; acc[0][2] += av##0 * wv.z; acc[0][3] += av##0 * wv.w; \
            acc[1][0] += av##1 * wv.x; acc[1][1] += av##1 * wv.y; acc[1][2] += av##1 * wv.z; acc[1][3] += av##1 * wv.w; \
            acc[2][0] += av##2 * wv.x; acc[2][1] += av##2 * wv.y; acc[2][2] += av##2 * wv.z; acc[2][3] += av##2 * wv.w; \
            acc[3][0] += av##3 * wv.x; acc[3][1] += av##3 * wv.y; acc[3][2] += av##3 * wv.z; acc[3][3] += av##3 * wv.w;
        { float ax0=a0.x, ax1=a1.x, ax2=a2.x, ax3=a3.x; STEP(ax, w0) }
        { float ay0=a0.y, ay1=a1.y, ay2=a2.y, ay3=a3.y; STEP(ay, w1) }
        { float az0=a0.z, az1=a1.z, az2=a2.z, az3=a3.z; STEP(az, w2) }
        { float aw0=a0.w, aw1=a1.w, aw2=a2.w, aw3=a3.w; STEP(aw, w3) }
        #undef STEP
    }
    const int pc = ct >> 3;
    const int cw = (ct & 7) * 4;
    for (int i = 0; i < 4; ++i) {
        int gr = base + rt * 4 + i;
        if (gr < N_NODES) {
            ushort4 u;
            u.x = __half_as_ushort(__float2half(acc[i][0]));
            u.y = __half_as_ushort(__float2half(acc[i][1]));
            u.z = __half_as_ushort(__float2half(acc[i][2]));
            u.w = __half_as_ushort(__float2half(acc[i][3]));
            *(ushort4*)&Yh[((size_t)pc * N_NODES + gr) * 32 + cw] = u;
        }
    }
}

// ---------- block sums + dinv (sums 8 shards) ----------
__global__ void block_sums_dinv(const unsigned long long* __restrict__ packed8,
                                int* __restrict__ bsum, float* __restrict__ dinv) {
    __shared__ int s[256];
    int idx = blockIdx.x * 256 + threadIdx.x;
    int c = 0;
    if (idx < N_NODES) {
        unsigned long long csum = 0, fsum = 0;
        #pragma unroll
        for (int sh = 0; sh < NSH; ++sh) {
            unsigned long long p = packed8[(size_t)sh * SH_STRIDE + idx];
            csum += p >> 32;
            fsum += p & 0xFFFFFFFFull;
        }
        c = (int)csum;
        dinv[idx] = rsqrtf((float)fsum * (1.0f / 16777216.0f) + 1.0f);
    }
    s[threadIdx.x] = c;
    __syncthreads();
    for (int o = 128; o; o >>= 1) {
        if (threadIdx.x < o) s[threadIdx.x] += s[threadIdx.x + o];
        __syncthreads();
    }
    if (threadIdx.x == 0) bsum[blockIdx.x] = s[0];
}

__global__ void scan_bsums(const int* __restrict__ bsum, int* __restrict__ boff,
                           int nb, int* __restrict__ row_start_last) {
    __shared__ int s[256];
    int v = (threadIdx.x < nb) ? bsum[threadIdx.x] : 0;
    s[threadIdx.x] = v;
    __syncthreads();
    for (int o = 1; o < 256; o <<= 1) {
        int t = 0;
        if (threadIdx.x >= o) t = s[threadIdx.x - o];
        __syncthreads();
        s[threadIdx.x] += t;
        __syncthreads();
    }
    if (threadIdx.x < nb) boff[threadIdx.x] = s[threadIdx.x] - v;   // exclusive
    if (threadIdx.x == 0) *row_start_last = N_EDGES;
}

// ---------- scan over nodes -> row_start; per-shard offsets -> soff[s][node] ----------
__global__ void scan_counts(const unsigned long long* __restrict__ packed8,
                            const int* __restrict__ boff, int* __restrict__ row_start,
                            int* __restrict__ soff) {
    __shared__ int s[256];
    int idx = blockIdx.x * 256 + threadIdx.x;
    int cs[NSH];
    int v = 0;
    if (idx < N_NODES) {
        #pragma unroll
        for (int sh = 0; sh < NSH; ++sh) {
            cs[sh] = (int)(packed8[(size_t)sh * SH_STRIDE + idx] >> 32);
            v += cs[sh];
        }
    }
    s[threadIdx.x] = v;
    __syncthreads();
    for (int o = 1; o < 256; o <<= 1) {
        int t = 0;
        if (threadIdx.x >= o) t = s[threadIdx.x - o];
        __syncthreads();
        s[threadIdx.x] += t;
        __syncthreads();
    }
    if (idx < N_NODES) {
        int ex = boff[blockIdx.x] + s[threadIdx.x] - v;   // exclusive scan (global row start)
        row_start[idx] = ex;
        int run = ex;
        #pragma unroll
        for (int sh = 0; sh < NSH; ++sh) {
            soff[(size_t)sh * SH_STRIDE + idx] = run;
            run += cs[sh];
        }
    }
}

// ---------- fill CSR: atomic-free, coef = dinv[s]*ew*dinv[d] as f16 ----------
__global__ void fill_direct(const int* __restrict__ src, const int* __restrict__ dst,
                            const float* __restrict__ ew, const unsigned short* __restrict__ pos16,
                            const int* __restrict__ soff, const float* __restrict__ dinv,
                            unsigned* __restrict__ csr) {
    int e = blockIdx.x * 256 + threadIdx.x;
    if (e < N_EDGES) {
        int d = __builtin_nontemporal_load(&dst[e]);
        int s = __builtin_nontemporal_load(&src[e]);
        float w = __builtin_nontemporal_load(&ew[e]);
        unsigned p16 = (unsigned)__builtin_nontemporal_load(&pos16[e]);
        int sh = (int)(p16 >> 12);
        int p  = (int)(p16 & 0xFFFu);
        float coef = dinv[s] * w * dinv[d];
        csr[soff[(size_t)sh * SH_STRIDE + d] + p] = ((unsigned)s << 16) | __half_as_ushort(__float2half(coef));
    }
}

// ---------- CSR aggregation: 64 lanes/node (16 feat-pairs x 4 edge-quarters) ----------
template<int NP, bool HOUT>
__global__ void agg_csr_pair(const int* __restrict__ row_start, const unsigned* __restrict__ csr,
                             const __half* __restrict__ xwh, const float* __restrict__ dinv,
                             const float* __restrict__ b, void* __restrict__ outp) {
    constexpr int OUT = NP * 32;
    const int c  = blockIdx.x % NP;
    const int nb = blockIdx.x / NP;
    const int n  = nb * 4 + (threadIdx.x >> 6);     // 4 nodes/block, one wave each
    const int kk = threadIdx.x & 15;                // feature pair
    const int q  = (threadIdx.x >> 4) & 3;          // edge quarter
    if (n >= N_NODES) return;
    const __half* __restrict__ bp = xwh + ((size_t)c * N_NODES) * 32 + 2 * kk;
    const int beg = row_start[n], end = row_start[n + 1];
    float ax = 0.f, ay = 0.f;
    int i = beg + q;
    for (; i + 12 < end; i += 16) {
        unsigned p0 = csr[i],     p1 = csr[i + 4];
        unsigned p2 = csr[i + 8], p3 = csr[i + 12];
        float2 f0 = __half22float2(*(const __half2*)(bp + (size_t)(p0 >> 16) * 32));
        float2 f1 = __half22float2(*(const __half2*)(bp + (size_t)(p1 >> 16) * 32));
        float2 f2 = __half22float2(*(const __half2*)(bp + (size_t)(p2 >> 16) * 32));
        float2 f3 = __half22float2(*(const __half2*)(bp + (size_t)(p3 >> 16) * 32));
        float e0 = coef_of(p0), e1 = coef_of(p1), e2 = coef_of(p2), e3 = coef_of(p3);
        ax += e0 * f0.x + e1 * f1.x + e2 * f2.x + e3 * f3.x;
        ay += e0 * f0.y + e1 * f1.y + e2 * f2.y + e3 * f3.y;
    }
    for (; i < end; i += 4) {
        unsigned p = csr[i];
        float2 f = __half22float2(*(const __half2*)(bp + (size_t)(p >> 16) * 32));
        float e = coef_of(p);
        ax += e * f.x; ay += e * f.y;
    }
    ax += __shfl_xor(ax, 16);  ay += __shfl_xor(ay, 16);
    ax += __shfl_xor(ax, 32);  ay += __shfl_xor(ay, 32);
    if (q == 0) {
        float2 sf = __half22float2(*(const __half2*)(bp + (size_t)n * 32));
        float dv = dinv[n];
        float dv2 = dv * dv;
        int kg = c * 32 + 2 * kk;
        float ox = fmaxf(ax + dv2 * sf.x + b[kg], 0.f);
        float oy = fmaxf(ay + dv2 * sf.y + b[kg + 1], 0.f);
        if constexpr (HOUT) {
            __half* o = (__half*)outp;
            *(__half2*)&o[(size_t)n * OUT + kg] = __floats2half2_rn(ox, oy);
        } else {
            float* o = (float*)outp;
            *(float2*)&o[(size_t)n * OUT + kg] = make_float2(ox, oy);
        }
    }
}

// ---------- GEMM2: Yh(raw f16 pair-major [2][N][32]) = Xh(f16 [N,128]) @ W[128,64] ----------
__global__ void gemm2_reg(const __half* __restrict__ Xh, const float* __restrict__ W,
                          __half* __restrict__ Yh, int nrows) {
    __shared__ float Xl[32][132];
    __shared__ float Wl[128][64];
    const int rt = threadIdx.x >> 5;
    const int ct = threadIdx.x & 31;
    const int base = blockIdx.x * 32;
    for (int i = threadIdx.x; i < 32 * 32; i += 256) {
        int rr = i >> 5, cc = (i & 31) << 2;
        int gr = base + rr;
        float2 fa = make_float2(0.f, 0.f), fb = fa;
        if (gr < nrows) {
            const __half2* ph = (const __half2*)&Xh[(size_t)gr * 128 + cc];
            fa = __half22float2(ph[0]);
            fb = __half22float2(ph[1]);
        }
        Xl[rr][cc] = fa.x; Xl[rr][cc + 1] = fa.y; Xl[rr][cc + 2] = fb.x; Xl[rr][cc + 3] = fb.y;
    }
    for (int i = threadIdx.x; i < 128 * 16; i += 256) {
        int kk = i >> 4, cc = (i & 15) << 2;
        *(float4*)&Wl[kk][cc] = *(const float4*)&W[(size_t)kk * 64 + cc];
    }
    float acc[4][2] = {};
    __syncthreads();
    for (int k = 0; k < 128; k += 4) {
        float4 a0 = *(const float4*)&Xl[rt * 4 + 0][k];
        float4 a1 = *(const float4*)&Xl[rt * 4 + 1][k];
        float4 a2 = *(const float4*)&Xl[rt * 4 + 2][k];
        float4 a3 = *(const float4*)&Xl[rt * 4 + 3][k];
        float2 w0 = *(const float2*)&Wl[k + 0][ct * 2];
        float2 w1 = *(const float2*)&Wl[k + 1][ct * 2];
        float2 w2 = *(const float2*)&Wl[k + 2][ct * 2];
        float2 w3 = *(const float2*)&Wl[k + 3][ct * 2];
        acc[0][0] += a0.x * w0.x; acc[0][1] += a0.x * w0.y;
        acc[1][0] += a1.x * w0.x; acc[1][1] += a1.x * w0.y;
        acc[2][0] += a2.x * w0.x; acc[2][1] += a2.x * w0.y;
        acc[3][0] += a3.x * w0.x; acc[3][1] += a3.x * w0.y;
        acc[0][0] += a0.y * w1.x; acc[0][1] += a0.y * w1.y;
        acc[1][0] += a1.y * w1.x; acc[1][1] += a1.y * w1.y;
        acc[2][0] += a2.y * w1.x; acc[2][1] += a2.y * w1.y;
        acc[3][0] += a3.y * w1.x; acc[3][1] += a3.y * w1.y;
        acc[0][0] += a0.z * w2.x; acc[0][1] += a0.z * w2.y;
        acc[1][0] += a1.z * w2.x; acc[1][1] += a1.z * w2.y;
        acc[2][0] += a2.z * w2.x; acc[2][1] += a2.z * w2.y;
        acc[3][0] += a3.z * w2.x; acc[3][1] += a3.z * w2.y;
        acc[0][0] += a0.w * w3.x; acc[0][1] += a0.w * w3.y;
        acc[1][0] += a1.w * w3.x; acc[1][1] += a1.w * w3.y;
        acc[2][0] += a2.w * w3.x; acc[2][1] += a2.w * w3.y;
        acc[3][0] += a3.w * w3.x; acc[3][1] += a3.w * w3.y;
    }
    const int col0 = ct * 2;
    const int pc   = col0 >> 5;
    const int cw   = col0 & 31;
    for (int i = 0; i < 4; ++i) {
        int gr = base + rt * 4 + i;
        if (gr < nrows) {
            __half2 hv = __floats2half2_rn(acc[i][0], acc[i][1]);
            *(__half2*)&Yh[((size_t)pc * nrows + gr) * 32 + cw] = hv;
        }
    }
}

// ---------- fused gate + exp + pool ----------
__global__ void gate_pool(const float* __restrict__ x1, const float* __restrict__ gW1,
                          const float* __restrict__ gb1, const float* __restrict__ gW2,
                          const float* __restrict__ gb2, const int* __restrict__ batch,
                          float* __restrict__ den, float* __restrict__ pooledU) {
    __shared__ float W1l[64 * 32];
    __shared__ float W2l[32];
    __shared__ float b1l[32];
    __shared__ float el[256];
    for (int i = threadIdx.x; i < 64 * 32; i += 256) W1l[i] = gW1[i];
    if (threadIdx.x < 32) { W2l[threadIdx.x] = gW2[threadIdx.x]; b1l[threadIdx.x] = gb1[threadIdx.x]; }
    __syncthreads();
    const float gb2v = gb2[0];
    const int n0 = blockIdx.x * 256;
    const int n = n0 + threadIdx.x;
    float ev = 0.f;
    if (n < N_NODES) {
        const float* row = x1 + (size_t)n * 64;
        float t[32];
        #pragma unroll
        for (int j = 0; j < 32; ++j) t[j] = b1l[j];
        for (int k = 0; k < 64; ++k) {
            float xv = row[k];
            #pragma unroll
            for (int j = 0; j < 32; ++j) t[j] += xv * W1l[k * 32 + j];
        }
        float a = gb2v;
        #pragma unroll
        for (int j = 0; j < 32; ++j) a += fmaxf(t[j], 0.f) * W2l[j];
        ev = expf(a);
    }
    el[threadIdx.x] = ev;
    __syncthreads();
    const int f   = threadIdx.x & 63;
    const int grp = threadIdx.x >> 6;
    int start = n0 + grp * 64;
    if (start >= N_NODES) return;
    int end = min(start + 64, N_NODES);
    int cur = batch[start];
    float acc = 0.f, accd = 0.f;
    for (int m = start; m < end; ++m) {
        int bb = batch[m];
        if (bb != cur) {
            atomicAdd(&pooledU[cur * 64 + f], acc);
            if (f == 0) atomicAdd(&den[cur], accd);
            acc = 0.f; accd = 0.f; cur = bb;
        }
        float e = el[m - n0];
        acc += e * x1[(size_t)m * 64 + f];
        if (f == 0) accd += e;
    }
    atomicAdd(&pooledU[cur * 64 + f], acc);
    if (f == 0) atomicAdd(&den[cur], accd);
}

// ---------- head: one block per graph; divides pooledU by den ----------
__global__ void head_kernel(const float* __restrict__ pooledU, const float* __restrict__ den,
                            const float* __restrict__ fcW1, const float* __restrict__ fcb1,
                            const float* __restrict__ fcW2, const float* __restrict__ fcb2,
                            float* __restrict__ out) {
    __shared__ float P[64];
    __shared__ float r0[2], r1[2];
    const int gi = blockIdx.x;
    if (threadIdx.x < 64) P[threadIdx.x] = pooledU[gi * 64 + threadIdx.x] / den[gi];
    __syncthreads();
    const int j = threadIdx.x;                     // 0..127
    float a = fcb1[j];
    #pragma unroll 8
    for (int k = 0; k < 64; ++k) a += P[k] * fcW1[k * 128 + j];
    float h = fmaxf(a, 0.f);
    float p0 = h * fcW2[j * 2 + 0];
    float p1 = h * fcW2[j * 2 + 1];
    for (int o = 32; o; o >>= 1) { p0 += __shfl_xor(p0, o); p1 += __shfl_xor(p1, o); }
    if ((threadIdx.x & 63) == 0) { r0[threadIdx.x >> 6] = p0; r1[threadIdx.x >> 6] = p1; }
    __syncthreads();
    if (threadIdx.x == 0) {
        float l0 = r0[0] + r0[1] + fcb2[0];
        float l1 = r1[0] + r1[1] + fcb2[1];
        float m = fmaxf(l0, l1);
        float lse = m + logf(expf(l0 - m) + expf(l1 - m));
        out[gi * 2 + 0] = l0 - lse;
        out[gi * 2 + 1] = l1 - lse;
    }
}

extern "C" void kernel_launch(void* const* d_in, const int* in_sizes, int n_in,
                              void* d_out, int out_size, void* d_ws, size_t ws_size,
                              hipStream_t stream) {
    const float* x    = (const float*)d_in[0];
    const int*   ei   = (const int*)d_in[1];
    const float* ew   = (const float*)d_in[2];
    const int*   batch= (const int*)d_in[3];
    const float* W1   = (const float*)d_in[4];
    const float* b1   = (const float*)d_in[5];
    const float* W2   = (const float*)d_in[6];
    const float* b2   = (const float*)d_in[7];
    const float* gW1  = (const float*)d_in[8];
    const float* gb1  = (const float*)d_in[9];
    const float* gW2  = (const float*)d_in[10];
    const float* gb2  = (const float*)d_in[11];
    const float* fcW1 = (const float*)d_in[12];
    const float* fcb1 = (const float*)d_in[13];
    const float* fcW2 = (const float*)d_in[14];
    const float* fcb2 = (const float*)d_in[15];
    float* out = (float*)d_out;

    const int* src = ei;
    const int* dst = ei + N_EDGES;

    const int EB = (N_EDGES + 255) / 256;          // 6250
    const int NB = (N_NODES + 255) / 256;          // 196
    const int NBLK4 = (N_NODES + 3) / 4;           // 12500

    // ---- workspace layout (floats) ----
    float* ws = (float*)d_ws;
    __half* xwh  = (__half*)ws;                    // raw f16 pair-major [NP][N][32] (6.4M halves)
    __half* hbuf = (__half*)(ws + 3200000);        // h f16 [N][128] (6.4M halves)
    float*  x1   = ws + 6400000;                   // x1 f32 [N][64]
    size_t off = 9600000;
    unsigned* csr   = (unsigned*)(ws + off); off += 1600000;  // packed (src<<16 | f16 coef)
    unsigned short* pos16 = (unsigned short*)(ws + off); off += 800000;
    int*   row_start= (int*)(ws + off);    off += 50176;
    unsigned long long* packed8 = (unsigned long long*)(ws + off); off += 2 * NSH * SH_STRIDE; // 3.2MB
    int*   soff     = (int*)(ws + off);    off += NSH * SH_STRIDE;                              // 1.6MB
    float* dinv     = ws + off;            off += 50176;
    int*   bsum     = (int*)(ws + off);    off += 256;
    int*   boff     = (int*)(ws + off);    off += 256;
    float* den      = ws + off;            off += 64;
    float* pooled   = ws + off;            off += 4096;

    // ---- memsets ----
    hipMemsetAsync(packed8, 0, (size_t)NSH * SH_STRIDE * sizeof(unsigned long long), stream);
    hipMemsetAsync(den, 0, (64 + 4096) * sizeof(float), stream);

    // ---- phase 1: gemm1 (raw f16) co-dispatched with sharded packed hist ----
    mega1<<<G1BLKS + EB, 256, 0, stream>>>(x, W1, xwh, dst, ew, packed8, pos16);

    // ---- CSR finish ----
    block_sums_dinv<<<NB, 256, 0, stream>>>(packed8, bsum, dinv);
    scan_bsums<<<1, 256, 0, stream>>>(bsum, boff, NB, row_start + N_NODES);
    scan_counts<<<NB, 256, 0, stream>>>(packed8, boff, row_start, soff);
    fill_direct<<<EB, 256, 0, stream>>>(src, dst, ew, pos16, soff, dinv, csr);

    // ---- conv1 agg -> h (f16 [N][128]) ----
    agg_csr_pair<4, true><<<4 * NBLK4, 256, 0, stream>>>(row_start, csr, xwh, dinv, b1, hbuf);

    // ---- conv2 ----
    gemm2_reg<<<(N_NODES + 31) / 32, 256, 0, stream>>>(hbuf, W2, xwh, N_NODES);
    agg_csr_pair<2, false><<<2 * NBLK4, 256, 0, stream>>>(row_start, csr, xwh, dinv, b2, x1);

    // ---- fused gate + exp + pool ----
    gate_pool<<<NB, 256, 0, stream>>>(x1, gW1, gb1, gW2, gb2, batch, den, pooled);

    // ---- head (64 blocks) ----
    head_kernel<<<N_GRAPHS, 128, 0, stream>>>(pooled, den, fcW1, fcb1, fcW2, fcb2, out);
}

// Round 13
// 308.437 us; speedup vs baseline: 1.2446x; 1.0929x over previous
//
#include <hip/hip_runtime.h>
#include <hip/hip_bf16.h>
#include <hip/hip_fp16.h>

#define N_NODES 50000
#define N_EDGES 1600000
#define N_GRAPHS 64
#define G1BLKS 1563            // ceil(N_NODES/32) gemm1 blocks in mega kernel
#define NSH 8                  // histogram shards (≈ XCDs)
#define SH_STRIDE 50048        // per-shard stride (≥ N_NODES, 64B aligned)
#define NBLK8 6250             // ceil(N_NODES/8) node-blocks for agg

// ---------- helpers ----------
__device__ __forceinline__ float coef_of(unsigned p) {
    return __half2float(__ushort_as_half((unsigned short)(p & 0xFFFFu)));
}

// ---------- MEGA: blocks [0,G1BLKS) = gemm1 (raw f16 out); rest = sharded packed hist ----------
// packed8[s][d]: high 32 = count, low 32 = sum(ew)*2^24 fixed point.
// pos16[e] = (shard<<12) | old_count_within_shard.
__global__ void mega1(const float* __restrict__ X, const float* __restrict__ W,
                      __half* __restrict__ Yh, const int* __restrict__ dst,
                      const float* __restrict__ ew,
                      unsigned long long* __restrict__ packed8,
                      unsigned short* __restrict__ pos16) {
    __shared__ float Xl[32][132];
    if (blockIdx.x >= G1BLKS) {
        const int sh = blockIdx.x & (NSH - 1);
        unsigned long long* __restrict__ pk = packed8 + (size_t)sh * SH_STRIDE;
        int e = (blockIdx.x - G1BLKS) * 256 + threadIdx.x;
        if (e < N_EDGES) {
            int d = __builtin_nontemporal_load(&dst[e]);
            float w = __builtin_nontemporal_load(&ew[e]);
            unsigned fix = (unsigned)(w * 16777216.0f);
            unsigned long long old = atomicAdd(&pk[d], 0x100000000ull | (unsigned long long)fix);
            pos16[e] = (unsigned short)((sh << 12) | (unsigned)(old >> 32));
        }
        return;
    }
    // ---- gemm1: Yh(f16 pair-major [4][N][32]) = X[N,128] @ W[128,128] (raw) ----
    const int rt = threadIdx.x >> 5;
    const int ct = threadIdx.x & 31;
    const int base = blockIdx.x * 32;
    for (int i = threadIdx.x; i < 32 * 32; i += 256) {
        int rr = i >> 5, cc = (i & 31) << 2;
        int gr = base + rr;
        float4 v = (gr < N_NODES) ? *(const float4*)&X[(size_t)gr * 128 + cc]
                                  : make_float4(0.f, 0.f, 0.f, 0.f);
        Xl[rr][cc] = v.x; Xl[rr][cc + 1] = v.y; Xl[rr][cc + 2] = v.z; Xl[rr][cc + 3] = v.w;
    }
    __syncthreads();
    float acc[4][4] = {};
    for (int k = 0; k < 128; k += 4) {
        float4 a0 = *(const float4*)&Xl[rt * 4 + 0][k];
        float4 a1 = *(const float4*)&Xl[rt * 4 + 1][k];
        float4 a2 = *(const float4*)&Xl[rt * 4 + 2][k];
        float4 a3 = *(const float4*)&Xl[rt * 4 + 3][k];
        float4 w0 = *(const float4*)&W[(size_t)(k + 0) * 128 + ct * 4];
        float4 w1 = *(const float4*)&W[(size_t)(k + 1) * 128 + ct * 4];
        float4 w2 = *(const float4*)&W[(size_t)(k + 2) * 128 + ct * 4];
        float4 w3 = *(const float4*)&W[(size_t)(k + 3) * 128 + ct * 4];
        #define STEP(av, wv)  \
            acc[0][0] += av##0 * wv.x; acc[0][1] += av##0 * wv.y; acc[0][2] += av##0 * wv.z; acc[0][3] += av##0 * wv.w; \
            acc[1][0] += av##1 * wv.x; acc[1][1] += av##1 * wv.y; acc[1][2] += av##1 * wv.z; acc[1][3] += av##1 * wv.w; \
            acc[2][0] += av##2 * wv.x; acc[2][1] += av##2 * wv.y; acc[2][2] += av##2 * wv.z; acc[2][3] += av##2 * wv.w; \
            acc[3][0] += av##3 * wv.x; acc[3][1] += av##3 * wv.y; acc[3][2] += av##3 * wv.z; acc[3][3] += av##3 * wv.w;
        { float ax0=a0.x, ax1=a1.x, ax2=a2.x, ax3=a3.x; STEP(ax, w0) }
        { float ay0=a0.y, ay1=a1.y, ay2=a2.y, ay3=a3.y; STEP(ay, w1) }
        { float az0=a0.z, az1=a1.z, az2=a2.z, az3=a3.z; STEP(az, w2) }
        { float aw0=a0.w, aw1=a1.w, aw2=a2.w, aw3=a3.w; STEP(aw, w3) }
        #undef STEP
    }
    const int pc = ct >> 3;
    const int cw = (ct & 7) * 4;
    for (int i = 0; i < 4; ++i) {
        int gr = base + rt * 4 + i;
        if (gr < N_NODES) {
            ushort4 u;
            u.x = __half_as_ushort(__float2half(acc[i][0]));
            u.y = __half_as_ushort(__float2half(acc[i][1]));
            u.z = __half_as_ushort(__float2half(acc[i][2]));
            u.w = __half_as_ushort(__float2half(acc[i][3]));
            *(ushort4*)&Yh[((size_t)pc * N_NODES + gr) * 32 + cw] = u;
        }
    }
}

// ---------- block sums + dinv (sums 8 shards) ----------
__global__ void block_sums_dinv(const unsigned long long* __restrict__ packed8,
                                int* __restrict__ bsum, float* __restrict__ dinv) {
    __shared__ int s[256];
    int idx = blockIdx.x * 256 + threadIdx.x;
    int c = 0;
    if (idx < N_NODES) {
        unsigned long long csum = 0, fsum = 0;
        #pragma unroll
        for (int sh = 0; sh < NSH; ++sh) {
            unsigned long long p = packed8[(size_t)sh * SH_STRIDE + idx];
            csum += p >> 32;
            fsum += p & 0xFFFFFFFFull;
        }
        c = (int)csum;
        dinv[idx] = rsqrtf((float)fsum * (1.0f / 16777216.0f) + 1.0f);
    }
    s[threadIdx.x] = c;
    __syncthreads();
    for (int o = 128; o; o >>= 1) {
        if (threadIdx.x < o) s[threadIdx.x] += s[threadIdx.x + o];
        __syncthreads();
    }
    if (threadIdx.x == 0) bsum[blockIdx.x] = s[0];
}

__global__ void scan_bsums(const int* __restrict__ bsum, int* __restrict__ boff,
                           int nb, int* __restrict__ row_start_last) {
    __shared__ int s[256];
    int v = (threadIdx.x < nb) ? bsum[threadIdx.x] : 0;
    s[threadIdx.x] = v;
    __syncthreads();
    for (int o = 1; o < 256; o <<= 1) {
        int t = 0;
        if (threadIdx.x >= o) t = s[threadIdx.x - o];
        __syncthreads();
        s[threadIdx.x] += t;
        __syncthreads();
    }
    if (threadIdx.x < nb) boff[threadIdx.x] = s[threadIdx.x] - v;   // exclusive
    if (threadIdx.x == 0) *row_start_last = N_EDGES;
}

// ---------- scan over nodes -> row_start; per-shard offsets -> soff[s][node] ----------
__global__ void scan_counts(const unsigned long long* __restrict__ packed8,
                            const int* __restrict__ boff, int* __restrict__ row_start,
                            int* __restrict__ soff) {
    __shared__ int s[256];
    int idx = blockIdx.x * 256 + threadIdx.x;
    int cs[NSH];
    int v = 0;
    if (idx < N_NODES) {
        #pragma unroll
        for (int sh = 0; sh < NSH; ++sh) {
            cs[sh] = (int)(packed8[(size_t)sh * SH_STRIDE + idx] >> 32);
            v += cs[sh];
        }
    }
    s[threadIdx.x] = v;
    __syncthreads();
    for (int o = 1; o < 256; o <<= 1) {
        int t = 0;
        if (threadIdx.x >= o) t = s[threadIdx.x - o];
        __syncthreads();
        s[threadIdx.x] += t;
        __syncthreads();
    }
    if (idx < N_NODES) {
        int ex = boff[blockIdx.x] + s[threadIdx.x] - v;   // exclusive scan (global row start)
        row_start[idx] = ex;
        int run = ex;
        #pragma unroll
        for (int sh = 0; sh < NSH; ++sh) {
            soff[(size_t)sh * SH_STRIDE + idx] = run;
            run += cs[sh];
        }
    }
}

// ---------- fill CSR: atomic-free, coef = dinv[s]*ew*dinv[d] as f16 ----------
__global__ void fill_direct(const int* __restrict__ src, const int* __restrict__ dst,
                            const float* __restrict__ ew, const unsigned short* __restrict__ pos16,
                            const int* __restrict__ soff, const float* __restrict__ dinv,
                            unsigned* __restrict__ csr) {
    int e = blockIdx.x * 256 + threadIdx.x;
    if (e < N_EDGES) {
        int d = __builtin_nontemporal_load(&dst[e]);
        int s = __builtin_nontemporal_load(&src[e]);
        float w = __builtin_nontemporal_load(&ew[e]);
        unsigned p16 = (unsigned)__builtin_nontemporal_load(&pos16[e]);
        int sh = (int)(p16 >> 12);
        int p  = (int)(p16 & 0xFFFu);
        float coef = dinv[s] * w * dinv[d];
        csr[soff[(size_t)sh * SH_STRIDE + d] + p] = ((unsigned)s << 16) | __half_as_ushort(__float2half(coef));
    }
}

// ---------- CSR aggregation: 32 lanes/node (16 feat-pairs x even/odd edges) ----------
// block mapping: c = blockIdx / NBLK8 (chunk), nb = blockIdx % NBLK8 (node range)
// -> consecutive blocks share a chunk: csr lines fetched once per pass per XCD.
template<int NP, bool HOUT>
__global__ void agg_csr_pair(const int* __restrict__ row_start, const unsigned* __restrict__ csr,
                             const __half* __restrict__ xwh, const float* __restrict__ dinv,
                             const float* __restrict__ b, void* __restrict__ outp) {
    constexpr int OUT = NP * 32;
    const int c    = blockIdx.x / NBLK8;
    const int nb   = blockIdx.x % NBLK8;
    const int n    = nb * 8 + (threadIdx.x >> 5);
    const int kk   = threadIdx.x & 15;
    const int half = (threadIdx.x >> 4) & 1;
    if (n >= N_NODES) return;
    const __half* __restrict__ bp = xwh + ((size_t)c * N_NODES) * 32 + 2 * kk;
    const int beg = row_start[n], end = row_start[n + 1];
    float ax = 0.f, ay = 0.f;
    int i = beg + half;
    for (; i + 6 < end; i += 8) {
        unsigned p0 = csr[i],     p1 = csr[i + 2];
        unsigned p2 = csr[i + 4], p3 = csr[i + 6];
        float2 f0 = __half22float2(*(const __half2*)(bp + (size_t)(p0 >> 16) * 32));
        float2 f1 = __half22float2(*(const __half2*)(bp + (size_t)(p1 >> 16) * 32));
        float2 f2 = __half22float2(*(const __half2*)(bp + (size_t)(p2 >> 16) * 32));
        float2 f3 = __half22float2(*(const __half2*)(bp + (size_t)(p3 >> 16) * 32));
        float e0 = coef_of(p0), e1 = coef_of(p1), e2 = coef_of(p2), e3 = coef_of(p3);
        ax += e0 * f0.x + e1 * f1.x + e2 * f2.x + e3 * f3.x;
        ay += e0 * f0.y + e1 * f1.y + e2 * f2.y + e3 * f3.y;
    }
    for (; i < end; i += 2) {
        unsigned p = csr[i];
        float2 f = __half22float2(*(const __half2*)(bp + (size_t)(p >> 16) * 32));
        float e = coef_of(p);
        ax += e * f.x; ay += e * f.y;
    }
    ax += __shfl_xor(ax, 16);
    ay += __shfl_xor(ay, 16);
    if (half == 0) {
        float2 sf = __half22float2(*(const __half2*)(bp + (size_t)n * 32));
        float dv = dinv[n];
        float dv2 = dv * dv;
        int kg = c * 32 + 2 * kk;
        float ox = fmaxf(ax + dv2 * sf.x + b[kg], 0.f);
        float oy = fmaxf(ay + dv2 * sf.y + b[kg + 1], 0.f);
        if constexpr (HOUT) {
            __half* o = (__half*)outp;
            *(__half2*)&o[(size_t)n * OUT + kg] = __floats2half2_rn(ox, oy);
        } else {
            float* o = (float*)outp;
            *(float2*)&o[(size_t)n * OUT + kg] = make_float2(ox, oy);
        }
    }
}

// ---------- GEMM2: Yh(raw f16 pair-major [2][N][32]) = Xh(f16 [N,128]) @ W[128,64] ----------
__global__ void gemm2_reg(const __half* __restrict__ Xh, const float* __restrict__ W,
                          __half* __restrict__ Yh, int nrows) {
    __shared__ float Xl[32][132];
    __shared__ float Wl[128][64];
    const int rt = threadIdx.x >> 5;
    const int ct = threadIdx.x & 31;
    const int base = blockIdx.x * 32;
    for (int i = threadIdx.x; i < 32 * 32; i += 256) {
        int rr = i >> 5, cc = (i & 31) << 2;
        int gr = base + rr;
        float2 fa = make_float2(0.f, 0.f), fb = fa;
        if (gr < nrows) {
            const __half2* ph = (const __half2*)&Xh[(size_t)gr * 128 + cc];
            fa = __half22float2(ph[0]);
            fb = __half22float2(ph[1]);
        }
        Xl[rr][cc] = fa.x; Xl[rr][cc + 1] = fa.y; Xl[rr][cc + 2] = fb.x; Xl[rr][cc + 3] = fb.y;
    }
    for (int i = threadIdx.x; i < 128 * 16; i += 256) {
        int kk = i >> 4, cc = (i & 15) << 2;
        *(float4*)&Wl[kk][cc] = *(const float4*)&W[(size_t)kk * 64 + cc];
    }
    float acc[4][2] = {};
    __syncthreads();
    for (int k = 0; k < 128; k += 4) {
        float4 a0 = *(const float4*)&Xl[rt * 4 + 0][k];
        float4 a1 = *(const float4*)&Xl[rt * 4 + 1][k];
        float4 a2 = *(const float4*)&Xl[rt * 4 + 2][k];
        float4 a3 = *(const float4*)&Xl[rt * 4 + 3][k];
        float2 w0 = *(const float2*)&Wl[k + 0][ct * 2];
        float2 w1 = *(const float2*)&Wl[k + 1][ct * 2];
        float2 w2 = *(const float2*)&Wl[k + 2][ct * 2];
        float2 w3 = *(const float2*)&Wl[k + 3][ct * 2];
        acc[0][0] += a0.x * w0.x; acc[0][1] += a0.x * w0.y;
        acc[1][0] += a1.x * w0.x; acc[1][1] += a1.x * w0.y;
        acc[2][0] += a2.x * w0.x; acc[2][1] += a2.x * w0.y;
        acc[3][0] += a3.x * w0.x; acc[3][1] += a3.x * w0.y;
        acc[0][0] += a0.y * w1.x; acc[0][1] += a0.y * w1.y;
        acc[1][0] += a1.y * w1.x; acc[1][1] += a1.y * w1.y;
        acc[2][0] += a2.y * w1.x; acc[2][1] += a2.y * w1.y;
        acc[3][0] += a3.y * w1.x; acc[3][1] += a3.y * w1.y;
        acc[0][0] += a0.z * w2.x; acc[0][1] += a0.z * w2.y;
        acc[1][0] += a1.z * w2.x; acc[1][1] += a1.z * w2.y;
        acc[2][0] += a2.z * w2.x; acc[2][1] += a2.z * w2.y;
        acc[3][0] += a3.z * w2.x; acc[3][1] += a3.z * w2.y;
        acc[0][0] += a0.w * w3.x; acc[0][1] += a0.w * w3.y;
        acc[1][0] += a1.w * w3.x; acc[1][1] += a1.w * w3.y;
        acc[2][0] += a2.w * w3.x; acc[2][1] += a2.w * w3.y;
        acc[3][0] += a3.w * w3.x; acc[3][1] += a3.w * w3.y;
    }
    const int col0 = ct * 2;
    const int pc   = col0 >> 5;
    const int cw   = col0 & 31;
    for (int i = 0; i < 4; ++i) {
        int gr = base + rt * 4 + i;
        if (gr < nrows) {
            __half2 hv = __floats2half2_rn(acc[i][0], acc[i][1]);
            *(__half2*)&Yh[((size_t)pc * nrows + gr) * 32 + cw] = hv;
        }
    }
}

// ---------- fused gate + exp + pool ----------
__global__ void gate_pool(const float* __restrict__ x1, const float* __restrict__ gW1,
                          const float* __restrict__ gb1, const float* __restrict__ gW2,
                          const float* __restrict__ gb2, const int* __restrict__ batch,
                          float* __restrict__ den, float* __restrict__ pooledU) {
    __shared__ float W1l[64 * 32];
    __shared__ float W2l[32];
    __shared__ float b1l[32];
    __shared__ float el[256];
    for (int i = threadIdx.x; i < 64 * 32; i += 256) W1l[i] = gW1[i];
    if (threadIdx.x < 32) { W2l[threadIdx.x] = gW2[threadIdx.x]; b1l[threadIdx.x] = gb1[threadIdx.x]; }
    __syncthreads();
    const float gb2v = gb2[0];
    const int n0 = blockIdx.x * 256;
    const int n = n0 + threadIdx.x;
    float ev = 0.f;
    if (n < N_NODES) {
        const float* row = x1 + (size_t)n * 64;
        float t[32];
        #pragma unroll
        for (int j = 0; j < 32; ++j) t[j] = b1l[j];
        for (int k = 0; k < 64; ++k) {
            float xv = row[k];
            #pragma unroll
            for (int j = 0; j < 32; ++j) t[j] += xv * W1l[k * 32 + j];
        }
        float a = gb2v;
        #pragma unroll
        for (int j = 0; j < 32; ++j) a += fmaxf(t[j], 0.f) * W2l[j];
        ev = expf(a);
    }
    el[threadIdx.x] = ev;
    __syncthreads();
    const int f   = threadIdx.x & 63;
    const int grp = threadIdx.x >> 6;
    int start = n0 + grp * 64;
    if (start >= N_NODES) return;
    int end = min(start + 64, N_NODES);
    int cur = batch[start];
    float acc = 0.f, accd = 0.f;
    for (int m = start; m < end; ++m) {
        int bb = batch[m];
        if (bb != cur) {
            atomicAdd(&pooledU[cur * 64 + f], acc);
            if (f == 0) atomicAdd(&den[cur], accd);
            acc = 0.f; accd = 0.f; cur = bb;
        }
        float e = el[m - n0];
        acc += e * x1[(size_t)m * 64 + f];
        if (f == 0) accd += e;
    }
    atomicAdd(&pooledU[cur * 64 + f], acc);
    if (f == 0) atomicAdd(&den[cur], accd);
}

// ---------- head: one block per graph; divides pooledU by den ----------
__global__ void head_kernel(const float* __restrict__ pooledU, const float* __restrict__ den,
                            const float* __restrict__ fcW1, const float* __restrict__ fcb1,
                            const float* __restrict__ fcW2, const float* __restrict__ fcb2,
                            float* __restrict__ out) {
    __shared__ float P[64];
    __shared__ float r0[2], r1[2];
    const int gi = blockIdx.x;
    if (threadIdx.x < 64) P[threadIdx.x] = pooledU[gi * 64 + threadIdx.x] / den[gi];
    __syncthreads();
    const int j = threadIdx.x;                     // 0..127
    float a = fcb1[j];
    #pragma unroll 8
    for (int k = 0; k < 64; ++k) a += P[k] * fcW1[k * 128 + j];
    float h = fmaxf(a, 0.f);
    float p0 = h * fcW2[j * 2 + 0];
    float p1 = h * fcW2[j * 2 + 1];
    for (int o = 32; o; o >>= 1) { p0 += __shfl_xor(p0, o); p1 += __shfl_xor(p1, o); }
    if ((threadIdx.x & 63) == 0) { r0[threadIdx.x >> 6] = p0; r1[threadIdx.x >> 6] = p1; }
    __syncthreads();
    if (threadIdx.x == 0) {
        float l0 = r0[0] + r0[1] + fcb2[0];
        float l1 = r1[0] + r1[1] + fcb2[1];
        float m = fmaxf(l0, l1);
        float lse = m + logf(expf(l0 - m) + expf(l1 - m));
        out[gi * 2 + 0] = l0 - lse;
        out[gi * 2 + 1] = l1 - lse;
    }
}

extern "C" void kernel_launch(void* const* d_in, const int* in_sizes, int n_in,
                              void* d_out, int out_size, void* d_ws, size_t ws_size,
                              hipStream_t stream) {
    const float* x    = (const float*)d_in[0];
    const int*   ei   = (const int*)d_in[1];
    const float* ew   = (const float*)d_in[2];
    const int*   batch= (const int*)d_in[3];
    const float* W1   = (const float*)d_in[4];
    const float* b1   = (const float*)d_in[5];
    const float* W2   = (const float*)d_in[6];
    const float* b2   = (const float*)d_in[7];
    const float* gW1  = (const float*)d_in[8];
    const float* gb1  = (const float*)d_in[9];
    const float* gW2  = (const float*)d_in[10];
    const float* gb2  = (const float*)d_in[11];
    const float* fcW1 = (const float*)d_in[12];
    const float* fcb1 = (const float*)d_in[13];
    const float* fcW2 = (const float*)d_in[14];
    const float* fcb2 = (const float*)d_in[15];
    float* out = (float*)d_out;

    const int* src = ei;
    const int* dst = ei + N_EDGES;

    const int EB = (N_EDGES + 255) / 256;          // 6250
    const int NB = (N_NODES + 255) / 256;          // 196

    // ---- workspace layout (floats) ----
    float* ws = (float*)d_ws;
    __half* xwh  = (__half*)ws;                    // raw f16 pair-major [NP][N][32] (6.4M halves)
    __half* hbuf = (__half*)(ws + 3200000);        // h f16 [N][128] (6.4M halves)
    float*  x1   = ws + 6400000;                   // x1 f32 [N][64]
    size_t off = 9600000;
    unsigned* csr   = (unsigned*)(ws + off); off += 1600000;  // packed (src<<16 | f16 coef)
    unsigned short* pos16 = (unsigned short*)(ws + off); off += 800000;
    int*   row_start= (int*)(ws + off);    off += 50176;
    unsigned long long* packed8 = (unsigned long long*)(ws + off); off += 2 * NSH * SH_STRIDE; // 3.2MB
    int*   soff     = (int*)(ws + off);    off += NSH * SH_STRIDE;                              // 1.6MB
    float* dinv     = ws + off;            off += 50176;
    int*   bsum     = (int*)(ws + off);    off += 256;
    int*   boff     = (int*)(ws + off);    off += 256;
    float* den      = ws + off;            off += 64;
    float* pooled   = ws + off;            off += 4096;

    // ---- memsets ----
    hipMemsetAsync(packed8, 0, (size_t)NSH * SH_STRIDE * sizeof(unsigned long long), stream);
    hipMemsetAsync(den, 0, (64 + 4096) * sizeof(float), stream);

    // ---- phase 1: gemm1 (raw f16) co-dispatched with sharded packed hist ----
    mega1<<<G1BLKS + EB, 256, 0, stream>>>(x, W1, xwh, dst, ew, packed8, pos16);

    // ---- CSR finish ----
    block_sums_dinv<<<NB, 256, 0, stream>>>(packed8, bsum, dinv);
    scan_bsums<<<1, 256, 0, stream>>>(bsum, boff, NB, row_start + N_NODES);
    scan_counts<<<NB, 256, 0, stream>>>(packed8, boff, row_start, soff);
    fill_direct<<<EB, 256, 0, stream>>>(src, dst, ew, pos16, soff, dinv, csr);

    // ---- conv1 agg -> h (f16 [N][128]) ----
    agg_csr_pair<4, true><<<4 * NBLK8, 256, 0, stream>>>(row_start, csr, xwh, dinv, b1, hbuf);

    // ---- conv2 ----
    gemm2_reg<<<(N_NODES + 31) / 32, 256, 0, stream>>>(hbuf, W2, xwh, N_NODES);
    agg_csr_pair<2, false><<<2 * NBLK8, 256, 0, stream>>>(row_start, csr, xwh, dinv, b2, x1);

    // ---- fused gate + exp + pool ----
    gate_pool<<<NB, 256, 0, stream>>>(x1, gW1, gb1, gW2, gb2, batch, den, pooled);

    // ---- head (64 blocks) ----
    head_kernel<<<N_GRAPHS, 128, 0, stream>>>(pooled, den, fcW1, fcb1, fcW2, fcb2, out);
}

// Round 14
// 298.086 us; speedup vs baseline: 1.2878x; 1.0347x over previous
//
#include <hip/hip_runtime.h>
#include <hip/hip_bf16.h>
#include <hip/hip_fp16.h>

#define N_NODES 50000
#define N_EDGES 1600000
#define N_GRAPHS 64
#define G1BLKS 1563            // ceil(N_NODES/32) gemm1 blocks in mega kernel
#define NSH 8                  // histogram shards (≈ XCDs)
#define SH_STRIDE 50048        // per-shard stride (≥ N_NODES, 64B aligned)
#define NBLK8 6250             // ceil(N_NODES/8) node-blocks for agg

// ---------- helpers ----------
__device__ __forceinline__ float coef_of(unsigned p) {
    return __half2float(__ushort_as_half((unsigned short)(p & 0xFFFFu)));
}

// ---------- MEGA: blocks [0,G1BLKS) = gemm1 (raw f16 out); rest = sharded packed hist ----------
__global__ void mega1(const float* __restrict__ X, const float* __restrict__ W,
                      __half* __restrict__ Yh, const int* __restrict__ dst,
                      const float* __restrict__ ew,
                      unsigned long long* __restrict__ packed8,
                      unsigned short* __restrict__ pos16) {
    __shared__ float Xl[32][132];
    if (blockIdx.x >= G1BLKS) {
        const int sh = blockIdx.x & (NSH - 1);
        unsigned long long* __restrict__ pk = packed8 + (size_t)sh * SH_STRIDE;
        int e = (blockIdx.x - G1BLKS) * 256 + threadIdx.x;
        if (e < N_EDGES) {
            int d = __builtin_nontemporal_load(&dst[e]);
            float w = __builtin_nontemporal_load(&ew[e]);
            unsigned fix = (unsigned)(w * 16777216.0f);
            unsigned long long old = atomicAdd(&pk[d], 0x100000000ull | (unsigned long long)fix);
            pos16[e] = (unsigned short)((sh << 12) | (unsigned)(old >> 32));
        }
        return;
    }
    const int rt = threadIdx.x >> 5;
    const int ct = threadIdx.x & 31;
    const int base = blockIdx.x * 32;
    for (int i = threadIdx.x; i < 32 * 32; i += 256) {
        int rr = i >> 5, cc = (i & 31) << 2;
        int gr = base + rr;
        float4 v = (gr < N_NODES) ? *(const float4*)&X[(size_t)gr * 128 + cc]
                                  : make_float4(0.f, 0.f, 0.f, 0.f);
        Xl[rr][cc] = v.x; Xl[rr][cc + 1] = v.y; Xl[rr][cc + 2] = v.z; Xl[rr][cc + 3] = v.w;
    }
    __syncthreads();
    float acc[4][4] = {};
    for (int k = 0; k < 128; k += 4) {
        float4 a0 = *(const float4*)&Xl[rt * 4 + 0][k];
        float4 a1 = *(const float4*)&Xl[rt * 4 + 1][k];
        float4 a2 = *(const float4*)&Xl[rt * 4 + 2][k];
        float4 a3 = *(const float4*)&Xl[rt * 4 + 3][k];
        float4 w0 = *(const float4*)&W[(size_t)(k + 0) * 128 + ct * 4];
        float4 w1 = *(const float4*)&W[(size_t)(k + 1) * 128 + ct * 4];
        float4 w2 = *(const float4*)&W[(size_t)(k + 2) * 128 + ct * 4];
        float4 w3 = *(const float4*)&W[(size_t)(k + 3) * 128 + ct * 4];
        #define STEP(av, wv)  \
            acc[0][0] += av##0 * wv.x; acc[0][1] += av##0 * wv.y; acc[0][2] += av##0 * wv.z; acc[0][3] += av##0 * wv.w; \
            acc[1][0] += av##1 * wv.x; acc[1][1] += av##1 * wv.y; acc[1][2] += av##1 * wv.z; acc[1][3] += av##1 * wv.w; \
            acc[2][0] += av##2 * wv.x; acc[2][1] += av##2 * wv.y; acc[2][2] += av##2 * wv.z; acc[2][3] += av##2 * wv.w; \
            acc[3][0] += av##3 * wv.x; acc[3][1] += av##3 * wv.y; acc[3][2] += av##3 * wv.z; acc[3][3] += av##3 * wv.w;
        { float ax0=a0.x, ax1=a1.x, ax2=a2.x, ax3=a3.x; STEP(ax, w0) }
        { float ay0=a0.y, ay1=a1.y, ay2=a2.y, ay3=a3.y; STEP(ay, w1) }
        { float az0=a0.z, az1=a1.z, az2=a2.z, az3=a3.z; STEP(az, w2) }
        { float aw0=a0.w, aw1=a1.w, aw2=a2.w, aw3=a3.w; STEP(aw, w3) }
        #undef STEP
    }
    const int pc = ct >> 3;
    const int cw = (ct & 7) * 4;
    for (int i = 0; i < 4; ++i) {
        int gr = base + rt * 4 + i;
        if (gr < N_NODES) {
            ushort4 u;
            u.x = __half_as_ushort(__float2half(acc[i][0]));
            u.y = __half_as_ushort(__float2half(acc[i][1]));
            u.z = __half_as_ushort(__float2half(acc[i][2]));
            u.w = __half_as_ushort(__float2half(acc[i][3]));
            *(ushort4*)&Yh[((size_t)pc * N_NODES + gr) * 32 + cw] = u;
        }
    }
}

// ---------- block sums + dinv (sums 8 shards) ----------
__global__ void block_sums_dinv(const unsigned long long* __restrict__ packed8,
                                int* __restrict__ bsum, float* __restrict__ dinv) {
    __shared__ int s[256];
    int idx = blockIdx.x * 256 + threadIdx.x;
    int c = 0;
    if (idx < N_NODES) {
        unsigned long long csum = 0, fsum = 0;
        #pragma unroll
        for (int sh = 0; sh < NSH; ++sh) {
            unsigned long long p = packed8[(size_t)sh * SH_STRIDE + idx];
            csum += p >> 32;
            fsum += p & 0xFFFFFFFFull;
        }
        c = (int)csum;
        dinv[idx] = rsqrtf((float)fsum * (1.0f / 16777216.0f) + 1.0f);
    }
    s[threadIdx.x] = c;
    __syncthreads();
    for (int o = 128; o; o >>= 1) {
        if (threadIdx.x < o) s[threadIdx.x] += s[threadIdx.x + o];
        __syncthreads();
    }
    if (threadIdx.x == 0) bsum[blockIdx.x] = s[0];
}

__global__ void scan_bsums(const int* __restrict__ bsum, int* __restrict__ boff,
                           int nb, int* __restrict__ row_start_last) {
    __shared__ int s[256];
    int v = (threadIdx.x < nb) ? bsum[threadIdx.x] : 0;
    s[threadIdx.x] = v;
    __syncthreads();
    for (int o = 1; o < 256; o <<= 1) {
        int t = 0;
        if (threadIdx.x >= o) t = s[threadIdx.x - o];
        __syncthreads();
        s[threadIdx.x] += t;
        __syncthreads();
    }
    if (threadIdx.x < nb) boff[threadIdx.x] = s[threadIdx.x] - v;   // exclusive
    if (threadIdx.x == 0) *row_start_last = N_EDGES;
}

__global__ void scan_counts(const unsigned long long* __restrict__ packed8,
                            const int* __restrict__ boff, int* __restrict__ row_start,
                            int* __restrict__ soff) {
    __shared__ int s[256];
    int idx = blockIdx.x * 256 + threadIdx.x;
    int cs[NSH];
    int v = 0;
    if (idx < N_NODES) {
        #pragma unroll
        for (int sh = 0; sh < NSH; ++sh) {
            cs[sh] = (int)(packed8[(size_t)sh * SH_STRIDE + idx] >> 32);
            v += cs[sh];
        }
    }
    s[threadIdx.x] = v;
    __syncthreads();
    for (int o = 1; o < 256; o <<= 1) {
        int t = 0;
        if (threadIdx.x >= o) t = s[threadIdx.x - o];
        __syncthreads();
        s[threadIdx.x] += t;
        __syncthreads();
    }
    if (idx < N_NODES) {
        int ex = boff[blockIdx.x] + s[threadIdx.x] - v;
        row_start[idx] = ex;
        int run = ex;
        #pragma unroll
        for (int sh = 0; sh < NSH; ++sh) {
            soff[(size_t)sh * SH_STRIDE + idx] = run;
            run += cs[sh];
        }
    }
}

// ---------- fill CSR: atomic-free, coef = dinv[s]*ew*dinv[d] as f16 ----------
__global__ void fill_direct(const int* __restrict__ src, const int* __restrict__ dst,
                            const float* __restrict__ ew, const unsigned short* __restrict__ pos16,
                            const int* __restrict__ soff, const float* __restrict__ dinv,
                            unsigned* __restrict__ csr) {
    int e = blockIdx.x * 256 + threadIdx.x;
    if (e < N_EDGES) {
        int d = __builtin_nontemporal_load(&dst[e]);
        int s = __builtin_nontemporal_load(&src[e]);
        float w = __builtin_nontemporal_load(&ew[e]);
        unsigned p16 = (unsigned)__builtin_nontemporal_load(&pos16[e]);
        int sh = (int)(p16 >> 12);
        int p  = (int)(p16 & 0xFFFu);
        float coef = dinv[s] * w * dinv[d];
        csr[soff[(size_t)sh * SH_STRIDE + d] + p] = ((unsigned)s << 16) | __half_as_ushort(__float2half(coef));
    }
}

// ---------- CSR aggregation: 32 lanes/node, chunk-major blocks, software-pipelined ----------
template<int NP, bool HOUT>
__global__ void agg_csr_pair(const int* __restrict__ row_start, const unsigned* __restrict__ csr,
                             const __half* __restrict__ xwh, const float* __restrict__ dinv,
                             const float* __restrict__ b, void* __restrict__ outp) {
    constexpr int OUT = NP * 32;
    const int c    = blockIdx.x / NBLK8;
    const int nb   = blockIdx.x % NBLK8;
    const int n    = nb * 8 + (threadIdx.x >> 5);
    const int kk   = threadIdx.x & 15;
    const int half = (threadIdx.x >> 4) & 1;
    if (n >= N_NODES) return;
    const __half* __restrict__ bp = xwh + ((size_t)c * N_NODES) * 32 + 2 * kk;
    const int beg = row_start[n], end = row_start[n + 1];
    float ax = 0.f, ay = 0.f;
    int i = beg + half;
    unsigned c0 = 0, c1 = 0, c2 = 0, c3 = 0;
    if (i + 6 < end) { c0 = csr[i]; c1 = csr[i + 2]; c2 = csr[i + 4]; c3 = csr[i + 6]; }
    while (i + 6 < end) {
        // issue gathers for current batch
        __half2 h0 = *(const __half2*)(bp + (size_t)(c0 >> 16) * 32);
        __half2 h1 = *(const __half2*)(bp + (size_t)(c1 >> 16) * 32);
        __half2 h2 = *(const __half2*)(bp + (size_t)(c2 >> 16) * 32);
        __half2 h3 = *(const __half2*)(bp + (size_t)(c3 >> 16) * 32);
        float e0 = coef_of(c0), e1 = coef_of(c1), e2 = coef_of(c2), e3 = coef_of(c3);
        // prefetch next batch's csr entries before consuming gathers
        int ni = i + 8;
        unsigned d0 = 0, d1 = 0, d2 = 0, d3 = 0;
        if (ni + 6 < end) { d0 = csr[ni]; d1 = csr[ni + 2]; d2 = csr[ni + 4]; d3 = csr[ni + 6]; }
        float2 f0 = __half22float2(h0), f1 = __half22float2(h1);
        float2 f2 = __half22float2(h2), f3 = __half22float2(h3);
        ax += e0 * f0.x + e1 * f1.x + e2 * f2.x + e3 * f3.x;
        ay += e0 * f0.y + e1 * f1.y + e2 * f2.y + e3 * f3.y;
        c0 = d0; c1 = d1; c2 = d2; c3 = d3;
        i = ni;
    }
    for (; i < end; i += 2) {
        unsigned p = csr[i];
        float2 f = __half22float2(*(const __half2*)(bp + (size_t)(p >> 16) * 32));
        float e = coef_of(p);
        ax += e * f.x; ay += e * f.y;
    }
    ax += __shfl_xor(ax, 16);
    ay += __shfl_xor(ay, 16);
    if (half == 0) {
        float2 sf = __half22float2(*(const __half2*)(bp + (size_t)n * 32));
        float dv = dinv[n];
        float dv2 = dv * dv;
        int kg = c * 32 + 2 * kk;
        float ox = fmaxf(ax + dv2 * sf.x + b[kg], 0.f);
        float oy = fmaxf(ay + dv2 * sf.y + b[kg + 1], 0.f);
        if constexpr (HOUT) {
            __half* o = (__half*)outp;
            *(__half2*)&o[(size_t)n * OUT + kg] = __floats2half2_rn(ox, oy);
        } else {
            float* o = (float*)outp;
            *(float2*)&o[(size_t)n * OUT + kg] = make_float2(ox, oy);
        }
    }
}

// ---------- GEMM2: Yh(raw f16 pair-major [2][N][32]) = Xh(f16 [N,128]) @ W[128,64] ----------
__global__ void gemm2_reg(const __half* __restrict__ Xh, const float* __restrict__ W,
                          __half* __restrict__ Yh, int nrows) {
    __shared__ float Xl[32][132];
    __shared__ float Wl[128][64];
    const int rt = threadIdx.x >> 5;
    const int ct = threadIdx.x & 31;
    const int base = blockIdx.x * 32;
    for (int i = threadIdx.x; i < 32 * 32; i += 256) {
        int rr = i >> 5, cc = (i & 31) << 2;
        int gr = base + rr;
        float2 fa = make_float2(0.f, 0.f), fb = fa;
        if (gr < nrows) {
            const __half2* ph = (const __half2*)&Xh[(size_t)gr * 128 + cc];
            fa = __half22float2(ph[0]);
            fb = __half22float2(ph[1]);
        }
        Xl[rr][cc] = fa.x; Xl[rr][cc + 1] = fa.y; Xl[rr][cc + 2] = fb.x; Xl[rr][cc + 3] = fb.y;
    }
    for (int i = threadIdx.x; i < 128 * 16; i += 256) {
        int kk = i >> 4, cc = (i & 15) << 2;
        *(float4*)&Wl[kk][cc] = *(const float4*)&W[(size_t)kk * 64 + cc];
    }
    float acc[4][2] = {};
    __syncthreads();
    for (int k = 0; k < 128; k += 4) {
        float4 a0 = *(const float4*)&Xl[rt * 4 + 0][k];
        float4 a1 = *(const float4*)&Xl[rt * 4 + 1][k];
        float4 a2 = *(const float4*)&Xl[rt * 4 + 2][k];
        float4 a3 = *(const float4*)&Xl[rt * 4 + 3][k];
        float2 w0 = *(const float2*)&Wl[k + 0][ct * 2];
        float2 w1 = *(const float2*)&Wl[k + 1][ct * 2];
        float2 w2 = *(const float2*)&Wl[k + 2][ct * 2];
        float2 w3 = *(const float2*)&Wl[k + 3][ct * 2];
        acc[0][0] += a0.x * w0.x; acc[0][1] += a0.x * w0.y;
        acc[1][0] += a1.x * w0.x; acc[1][1] += a1.x * w0.y;
        acc[2][0] += a2.x * w0.x; acc[2][1] += a2.x * w0.y;
        acc[3][0] += a3.x * w0.x; acc[3][1] += a3.x * w0.y;
        acc[0][0] += a0.y * w1.x; acc[0][1] += a0.y * w1.y;
        acc[1][0] += a1.y * w1.x; acc[1][1] += a1.y * w1.y;
        acc[2][0] += a2.y * w1.x; acc[2][1] += a2.y * w1.y;
        acc[3][0] += a3.y * w1.x; acc[3][1] += a3.y * w1.y;
        acc[0][0] += a0.z * w2.x; acc[0][1] += a0.z * w2.y;
        acc[1][0] += a1.z * w2.x; acc[1][1] += a1.z * w2.y;
        acc[2][0] += a2.z * w2.x; acc[2][1] += a2.z * w2.y;
        acc[3][0] += a3.z * w2.x; acc[3][1] += a3.z * w2.y;
        acc[0][0] += a0.w * w3.x; acc[0][1] += a0.w * w3.y;
        acc[1][0] += a1.w * w3.x; acc[1][1] += a1.w * w3.y;
        acc[2][0] += a2.w * w3.x; acc[2][1] += a2.w * w3.y;
        acc[3][0] += a3.w * w3.x; acc[3][1] += a3.w * w3.y;
    }
    const int col0 = ct * 2;
    const int pc   = col0 >> 5;
    const int cw   = col0 & 31;
    for (int i = 0; i < 4; ++i) {
        int gr = base + rt * 4 + i;
        if (gr < nrows) {
            __half2 hv = __floats2half2_rn(acc[i][0], acc[i][1]);
            *(__half2*)&Yh[((size_t)pc * nrows + gr) * 32 + cw] = hv;
        }
    }
}

// ---------- fused gate + exp + pool, x1 staged in LDS (coalesced f16 loads) ----------
__global__ void gate_pool(const __half* __restrict__ x1h, const float* __restrict__ gW1,
                          const float* __restrict__ gb1, const float* __restrict__ gW2,
                          const float* __restrict__ gb2, const int* __restrict__ batch,
                          float* __restrict__ den, float* __restrict__ pooledU) {
    __shared__ float W1l[64 * 32];    // 8 KB
    __shared__ float W2l[32];
    __shared__ float b1l[32];
    __shared__ float Xs[256][65];     // 66.56 KB (pad 65 -> conflict-free both phases)
    __shared__ float el[256];         // 1 KB
    for (int i = threadIdx.x; i < 64 * 32; i += 256) W1l[i] = gW1[i];
    if (threadIdx.x < 32) { W2l[threadIdx.x] = gW2[threadIdx.x]; b1l[threadIdx.x] = gb1[threadIdx.x]; }
    const int n0 = blockIdx.x * 256;
    // stage 256 rows x 64 f16 feats, coalesced (16 x ushort4 per row)
    for (int i = threadIdx.x; i < 256 * 16; i += 256) {
        int r = i >> 4, c4 = (i & 15) << 2;
        int nn = n0 + r;
        if (nn < N_NODES) {
            ushort4 u = *(const ushort4*)&x1h[(size_t)nn * 64 + c4];
            Xs[r][c4 + 0] = __half2float(__ushort_as_half(u.x));
            Xs[r][c4 + 1] = __half2float(__ushort_as_half(u.y));
            Xs[r][c4 + 2] = __half2float(__ushort_as_half(u.z));
            Xs[r][c4 + 3] = __half2float(__ushort_as_half(u.w));
        } else {
            Xs[r][c4 + 0] = 0.f; Xs[r][c4 + 1] = 0.f;
            Xs[r][c4 + 2] = 0.f; Xs[r][c4 + 3] = 0.f;
        }
    }
    __syncthreads();
    const float gb2v = gb2[0];
    const int n = n0 + threadIdx.x;
    float ev = 0.f;
    if (n < N_NODES) {
        float t[32];
        #pragma unroll
        for (int j = 0; j < 32; ++j) t[j] = b1l[j];
        for (int k = 0; k < 64; ++k) {
            float xv = Xs[threadIdx.x][k];
            #pragma unroll
            for (int j = 0; j < 32; ++j) t[j] += xv * W1l[k * 32 + j];
        }
        float a = gb2v;
        #pragma unroll
        for (int j = 0; j < 32; ++j) a += fmaxf(t[j], 0.f) * W2l[j];
        ev = expf(a);
    }
    el[threadIdx.x] = ev;
    __syncthreads();
    const int f   = threadIdx.x & 63;
    const int grp = threadIdx.x >> 6;
    int start = n0 + grp * 64;
    if (start >= N_NODES) return;
    int end = min(start + 64, N_NODES);
    int cur = batch[start];
    float acc = 0.f, accd = 0.f;
    for (int m = start; m < end; ++m) {
        int bb = batch[m];
        if (bb != cur) {
            atomicAdd(&pooledU[cur * 64 + f], acc);
            if (f == 0) atomicAdd(&den[cur], accd);
            acc = 0.f; accd = 0.f; cur = bb;
        }
        float e = el[m - n0];
        acc += e * Xs[m - n0][f];
        if (f == 0) accd += e;
    }
    atomicAdd(&pooledU[cur * 64 + f], acc);
    if (f == 0) atomicAdd(&den[cur], accd);
}

// ---------- head: one block per graph; divides pooledU by den ----------
__global__ void head_kernel(const float* __restrict__ pooledU, const float* __restrict__ den,
                            const float* __restrict__ fcW1, const float* __restrict__ fcb1,
                            const float* __restrict__ fcW2, const float* __restrict__ fcb2,
                            float* __restrict__ out) {
    __shared__ float P[64];
    __shared__ float r0[2], r1[2];
    const int gi = blockIdx.x;
    if (threadIdx.x < 64) P[threadIdx.x] = pooledU[gi * 64 + threadIdx.x] / den[gi];
    __syncthreads();
    const int j = threadIdx.x;
    float a = fcb1[j];
    #pragma unroll 8
    for (int k = 0; k < 64; ++k) a += P[k] * fcW1[k * 128 + j];
    float h = fmaxf(a, 0.f);
    float p0 = h * fcW2[j * 2 + 0];
    float p1 = h * fcW2[j * 2 + 1];
    for (int o = 32; o; o >>= 1) { p0 += __shfl_xor(p0, o); p1 += __shfl_xor(p1, o); }
    if ((threadIdx.x & 63) == 0) { r0[threadIdx.x >> 6] = p0; r1[threadIdx.x >> 6] = p1; }
    __syncthreads();
    if (threadIdx.x == 0) {
        float l0 = r0[0] + r0[1] + fcb2[0];
        float l1 = r1[0] + r1[1] + fcb2[1];
        float m = fmaxf(l0, l1);
        float lse = m + logf(expf(l0 - m) + expf(l1 - m));
        out[gi * 2 + 0] = l0 - lse;
        out[gi * 2 + 1] = l1 - lse;
    }
}

extern "C" void kernel_launch(void* const* d_in, const int* in_sizes, int n_in,
                              void* d_out, int out_size, void* d_ws, size_t ws_size,
                              hipStream_t stream) {
    const float* x    = (const float*)d_in[0];
    const int*   ei   = (const int*)d_in[1];
    const float* ew   = (const float*)d_in[2];
    const int*   batch= (const int*)d_in[3];
    const float* W1   = (const float*)d_in[4];
    const float* b1   = (const float*)d_in[5];
    const float* W2   = (const float*)d_in[6];
    const float* b2   = (const float*)d_in[7];
    const float* gW1  = (const float*)d_in[8];
    const float* gb1  = (const float*)d_in[9];
    const float* gW2  = (const float*)d_in[10];
    const float* gb2  = (const float*)d_in[11];
    const float* fcW1 = (const float*)d_in[12];
    const float* fcb1 = (const float*)d_in[13];
    const float* fcW2 = (const float*)d_in[14];
    const float* fcb2 = (const float*)d_in[15];
    float* out = (float*)d_out;

    const int* src = ei;
    const int* dst = ei + N_EDGES;

    const int EB = (N_EDGES + 255) / 256;          // 6250
    const int NB = (N_NODES + 255) / 256;          // 196

    // ---- workspace layout (floats) ----
    float* ws = (float*)d_ws;
    __half* xwh  = (__half*)ws;                    // raw f16 pair-major [NP][N][32] (6.4M halves)
    __half* hbuf = (__half*)(ws + 3200000);        // h f16 [N][128] (6.4M halves)
    __half* x1h  = (__half*)(ws + 6400000);        // x1 f16 [N][64] (3.2M halves)
    size_t off = 9600000;
    unsigned* csr   = (unsigned*)(ws + off); off += 1600000;
    unsigned short* pos16 = (unsigned short*)(ws + off); off += 800000;
    int*   row_start= (int*)(ws + off);    off += 50176;
    unsigned long long* packed8 = (unsigned long long*)(ws + off); off += 2 * NSH * SH_STRIDE;
    int*   soff     = (int*)(ws + off);    off += NSH * SH_STRIDE;
    float* dinv     = ws + off;            off += 50176;
    int*   bsum     = (int*)(ws + off);    off += 256;
    int*   boff     = (int*)(ws + off);    off += 256;
    float* den      = ws + off;            off += 64;
    float* pooled   = ws + off;            off += 4096;

    // ---- memsets ----
    hipMemsetAsync(packed8, 0, (size_t)NSH * SH_STRIDE * sizeof(unsigned long long), stream);
    hipMemsetAsync(den, 0, (64 + 4096) * sizeof(float), stream);

    // ---- phase 1: gemm1 (raw f16) co-dispatched with sharded packed hist ----
    mega1<<<G1BLKS + EB, 256, 0, stream>>>(x, W1, xwh, dst, ew, packed8, pos16);

    // ---- CSR finish ----
    block_sums_dinv<<<NB, 256, 0, stream>>>(packed8, bsum, dinv);
    scan_bsums<<<1, 256, 0, stream>>>(bsum, boff, NB, row_start + N_NODES);
    scan_counts<<<NB, 256, 0, stream>>>(packed8, boff, row_start, soff);
    fill_direct<<<EB, 256, 0, stream>>>(src, dst, ew, pos16, soff, dinv, csr);

    // ---- conv1 agg -> h (f16 [N][128]) ----
    agg_csr_pair<4, true><<<4 * NBLK8, 256, 0, stream>>>(row_start, csr, xwh, dinv, b1, hbuf);

    // ---- conv2 ----
    gemm2_reg<<<(N_NODES + 31) / 32, 256, 0, stream>>>(hbuf, W2, xwh, N_NODES);
    agg_csr_pair<2, true><<<2 * NBLK8, 256, 0, stream>>>(row_start, csr, xwh, dinv, b2, x1h);

    // ---- fused gate + exp + pool (x1 staged in LDS) ----
    gate_pool<<<NB, 256, 0, stream>>>(x1h, gW1, gb1, gW2, gb2, batch, den, pooled);

    // ---- head (64 blocks) ----
    head_kernel<<<N_GRAPHS, 128, 0, stream>>>(pooled, den, fcW1, fcb1, fcW2, fcb2, out);
}